// Round 18
// baseline (567.198 us; speedup 1.0000x reference)
//
#include <hip/hip_runtime.h>
#include <hip/hip_bf16.h>

// ---------------------------------------------------------------------------
// Attention block: B=2 S=2048 D=4096 H=32 KV=8 HD=128 (GQA N_REP=4, causal)
// Pipeline: cvt -> GEMM-qkv(256x192, FUSED RoPE epilogue) ->
//           flash-attn(4-wave, 2 blocks/CU) -> GEMM8-256sq(out)
// ---------------------------------------------------------------------------

typedef __attribute__((ext_vector_type(8)))  short s8v;   // 8 x bf16 (4 VGPR)
typedef __attribute__((ext_vector_type(4)))  short s4v;   // 4 x bf16 (2 VGPR)
typedef __attribute__((ext_vector_type(4)))  float f4v;
typedef __attribute__((ext_vector_type(16))) float f16v;  // 32x32 MFMA acc
typedef __attribute__((ext_vector_type(2)))  float f2v;
typedef __attribute__((ext_vector_type(2))) unsigned int u2v;
typedef __attribute__((ext_vector_type(4))) unsigned int u4v;

typedef __attribute__((address_space(3))) void lds_void;
typedef __attribute__((address_space(1))) void g_void;

#define GLDS16(gp, lp) __builtin_amdgcn_global_load_lds((g_void*)(gp), (lds_void*)(lp), 16, 0, 0)

#define SCL_LOG2 0.12751744f   // (1/sqrt(128)) * log2(e); folded into Q at rope-fusion

__device__ __forceinline__ unsigned short f2b(float f) {  // f32 -> bf16 RNE
  unsigned u = __builtin_bit_cast(unsigned, f);
  u += 0x7fffu + ((u >> 16) & 1u);
  return (unsigned short)(u >> 16);
}
__device__ __forceinline__ unsigned pk2(float a, float b) {
  return (unsigned)f2b(a) | ((unsigned)f2b(b) << 16);
}
__device__ __forceinline__ float b2f(unsigned short h) {
  return __builtin_bit_cast(float, (unsigned)h << 16);
}

// inline-asm MFMAs (volatile; s_nop guards at every MFMA->VALU read-back)
__device__ __forceinline__ void mfma32(f4v& d, s8v a, s8v b) {
  asm volatile("v_mfma_f32_16x16x32_bf16 %0, %1, %2, %0" : "+v"(d) : "v"(a), "v"(b));
}
__device__ __forceinline__ void mfma3216(f16v& d, s8v a, s8v b) {
  asm volatile("v_mfma_f32_32x32x16_bf16 %0, %1, %2, %0" : "+v"(d) : "v"(a), "v"(b));
}
__device__ __forceinline__ s4v tr_read(const char* p, int imm) {
  s4v r;
  asm volatile("ds_read_b64_tr_b16 %0, %1 offset:%2"
               : "=v"(r) : "v"((lds_void*)p), "n"(imm));
  return r;
}

// ---------------------------------------------------------------------------
// f32 -> bf16 convert
// ---------------------------------------------------------------------------
__global__ __launch_bounds__(256) void cvt_bf16(const float* __restrict__ s,
                                                unsigned short* __restrict__ d, int n4) {
  const int i = blockIdx.x * 256 + threadIdx.x;
  if (i >= n4) return;
  f4v v = *(const f4v*)(s + (size_t)i * 4);
  u2v r;
  r.x = pk2(v[0], v[1]);
  r.y = pk2(v[2], v[3]);
  *(u2v*)(d + (size_t)i * 4) = r;
}

// ---------------------------------------------------------------------------
// sync macros shared by GEMM kernels
// ---------------------------------------------------------------------------
#define BAR      asm volatile("s_barrier" ::: "memory")
#define WLGKM    do { asm volatile("s_waitcnt lgkmcnt(0)" ::: "memory"); \
                      __builtin_amdgcn_sched_barrier(0); } while (0)
#define WVM8     do { asm volatile("s_waitcnt vmcnt(8)" ::: "memory"); \
                      __builtin_amdgcn_sched_barrier(0); } while (0)
#define WVM7     do { asm volatile("s_waitcnt vmcnt(7)" ::: "memory"); \
                      __builtin_amdgcn_sched_barrier(0); } while (0)

// ---------------------------------------------------------------------------
// qkv GEMM: 256x192 tile, full K=4096, 512 blocks = 2 exact rounds.
// Round-18: RoPE FUSED into the epilogue. Each lane holds C[row][col] f32;
// the rotation pair (2j,2j+1) lives in lane pair l,l^1 (col parity == qi
// parity, tile bases even). One shfl_xor(v,1) BEFORE the range branch gives
// both operands; rotate in f32; write qbuf (pre-scaled bf16), kbuf+xk, or
// vbuf+xv per column range (boundary tiles straddle 4096/5120: per-element
// predication). Eliminates the rope pass entirely (~130 MB traffic).
// ---------------------------------------------------------------------------
__global__ __launch_bounds__(512, 2) void gemm_qkv(const unsigned short* __restrict__ A,
                                                   const unsigned short* __restrict__ Bp,
                                                   const float* __restrict__ fr,
                                                   const float* __restrict__ fi,
                                                   unsigned short* __restrict__ qbuf,
                                                   unsigned short* __restrict__ kbuf,
                                                   unsigned short* __restrict__ vbuf,
                                                   float* __restrict__ xk,
                                                   float* __restrict__ xv) {
  __shared__ __align__(16) char smem[114688];
  const int tid = threadIdx.x, lane = tid & 63, wv = tid >> 6;
  const int qi = lane & 15, g = lane >> 4;
  const int wm = wv >> 1, wn = wv & 1;          // 4M x 2N
  const int K = 4096, NT = 64;

  const int id = blockIdx.x;
  const int swz = (id & 7) * 64 + (id >> 3);
  const int m0 = (swz & 15) * 256, n0 = (swz >> 4) * 192;

  const int srowo = wv * 8 + (lane >> 3);
  const int scole = ((lane & 7) ^ (lane >> 3)) << 3;
  const size_t rA = (size_t)(m0 + srowo) * K + scole;
  const size_t rB = (size_t)(n0 + srowo) * K + scole;
  char* sdA = smem + wv * 1024;
  char* sdB = smem + 65536 + wv * 1024;

#define QSTG_A(D, KT) do { _Pragma("unroll") for (int c_ = 0; c_ < 4; ++c_) \
    GLDS16(A + rA + (size_t)(c_ * 64) * K + (size_t)(KT) * 64, \
           sdA + (D) * 32768 + c_ * 8192); } while (0)
#define QSTG_B(D, KT) do { _Pragma("unroll") for (int c_ = 0; c_ < 3; ++c_) \
    GLDS16(Bp + rB + (size_t)(c_ * 64) * K + (size_t)(KT) * 64, \
           sdB + (D) * 24576 + c_ * 8192); } while (0)

  const int sw = (qi & 7) << 4;
  const char* frA = smem + (wm * 64 + qi) * 128;
  const char* frB = smem + 65536 + (wn * 96 + qi) * 128;

#define QRDA(D, F0) do { _Pragma("unroll") for (int f_ = 0; f_ < 2; ++f_) \
    _Pragma("unroll") for (int k_ = 0; k_ < 2; ++k_) \
      a[(F0) + f_][k_] = *(const s8v*)(frA + (D) * 32768 + ((F0) + f_) * 2048 + (((k_ << 6) + (g << 4)) ^ sw)); } while (0)
#define QRDB(D, N0) do { _Pragma("unroll") for (int n_ = 0; n_ < 3; ++n_) \
    _Pragma("unroll") for (int k_ = 0; k_ < 2; ++k_) \
      b[(N0) + n_][k_] = *(const s8v*)(frB + (D) * 24576 + ((N0) + n_) * 2048 + (((k_ << 6) + (g << 4)) ^ sw)); } while (0)
#define QMQUAD(F0, N0) do { __builtin_amdgcn_s_setprio(1); \
    _Pragma("unroll") for (int f_ = 0; f_ < 2; ++f_) \
    _Pragma("unroll") for (int n_ = 0; n_ < 3; ++n_) \
    _Pragma("unroll") for (int k_ = 0; k_ < 2; ++k_) \
      mfma32(acc[(F0) + f_][(N0) + n_], a[(F0) + f_][k_], b[(N0) + n_][k_]); \
    __builtin_amdgcn_s_setprio(0); } while (0)

  f4v acc[4][6];
#pragma unroll
  for (int i = 0; i < 4; ++i)
#pragma unroll
    for (int j = 0; j < 6; ++j) acc[i][j] = (f4v)0.0f;

  QSTG_A(0, 0); QSTG_B(0, 0);
  QSTG_A(1, 1); QSTG_B(1, 1);
  WVM7;
  BAR;

  s8v a[4][2], b[6][2];
#pragma unroll 1
  for (int it = 0; it < NT / 2; ++it) {
    const int t = 2 * it;
    const int k2 = (t + 2 < NT) ? t + 2 : NT - 1;
    const int k3 = (t + 3 < NT) ? t + 3 : NT - 1;
    QRDA(0, 0); QRDB(0, 0);
    WLGKM; QMQUAD(0, 0); BAR;
    QRDB(0, 3);
    WLGKM; QMQUAD(0, 3); BAR;
    QRDA(0, 2);
    QSTG_B(0, k2);
    WLGKM; QMQUAD(2, 0); BAR;
    QSTG_A(0, k2);
    QMQUAD(2, 3);
    WVM7; BAR;
    QRDA(1, 0); QRDB(1, 0);
    WLGKM; QMQUAD(0, 0); BAR;
    QRDB(1, 3);
    WLGKM; QMQUAD(0, 3); BAR;
    QRDA(1, 2);
    QSTG_B(1, k3);
    WLGKM; QMQUAD(2, 0); BAR;
    QSTG_A(1, k3);
    QMQUAD(2, 3);
    WVM7; BAR;
  }

  asm volatile("s_waitcnt vmcnt(0)" ::: "memory");
  asm volatile("s_nop 7\n\ts_nop 7" ::: "memory");   // MFMA->VALU hazard guard
  // ---- fused RoPE epilogue ----
  const int r4 = g * 4;
  const int even = !(qi & 1);
#pragma unroll
  for (int fm = 0; fm < 4; ++fm)
#pragma unroll
    for (int fn = 0; fn < 6; ++fn)
#pragma unroll
      for (int r = 0; r < 4; ++r) {
        const int row = m0 + wm * 64 + fm * 16 + r4 + r;   // token (b*2048+s)
        const int col = n0 + wn * 96 + fn * 16 + qi;
        const float v = acc[fm][fn][r];
        const float pv = __shfl_xor(v, 1);                 // partner (before branch)
        const float v0 = even ? v : pv;
        const float v1 = even ? pv : v;
        const int pos = row & 2047;
        const int j = (col & 127) >> 1;
        if (col < 4096) {                                  // Q: rope + scale
          const float cr = fr[pos * 64 + j], ci = fi[pos * 64 + j];
          const float q = (even ? (v0 * cr - ci * v1) : (v0 * ci + v1 * cr)) * SCL_LOG2;
          qbuf[(size_t)row * 4096 + col] = f2b(q);
        } else if (col < 5120) {                           // K: rope + f32 out
          const int lc = col - 4096;
          const float cr = fr[pos * 64 + j], ci = fi[pos * 64 + j];
          const float kv = even ? (v0 * cr - ci * v1) : (v0 * ci + v1 * cr);
          kbuf[(size_t)row * 1024 + lc] = f2b(kv);
          xk[(size_t)row * 1024 + lc] = kv;
        } else {                                           // V: copy + f32 out
          const int lc = col - 5120;
          vbuf[(size_t)row * 1024 + lc] = f2b(v);
          xv[(size_t)row * 1024 + lc] = v;
        }
      }
}

// ---------------------------------------------------------------------------
// 8-phase 256-sq GEMM (round-10 schedule v3, proven) — used for out-proj.
// ---------------------------------------------------------------------------
template <int OUTB>
__global__ __launch_bounds__(512, 2) void gemm_bt8(const unsigned short* __restrict__ A,
                                                   const unsigned short* __restrict__ Bp,
                                                   void* __restrict__ Cout,
                                                   int M, int N, int Ks, int Klen,
                                                   int nTiles) {
  __shared__ __align__(16) char smem[131072];
  const int tid = threadIdx.x, lane = tid & 63, wv = tid >> 6;
  const int qi = lane & 15, g = lane >> 4;
  const int wm = wv >> 2, wn = wv & 3;

  const int nwg = gridDim.x, cpx = nwg >> 3;
  const int id = blockIdx.x;
  const int swz = (id & 7) * cpx + (id >> 3);
  const int half = swz / nTiles;
  const int tile = swz - half * nTiles;
  const int kOff = half * Klen;
  const int MT = M >> 8;
  const int m0 = (tile % MT) * 256, n0 = (tile / MT) * 256;
  const int NT = Klen >> 6;

  const int srowo = wv * 8 + (lane >> 3);
  const int scole = ((lane & 7) ^ (lane >> 3)) << 3;
  const size_t rA = (size_t)(m0 + srowo) * Ks + kOff + scole;
  const size_t rB = (size_t)(n0 + srowo) * Ks + kOff + scole;
  char* sdA = smem + wv * 1024;
  char* sdB = smem + 32768 + wv * 1024;

#define STG_A(D, H, KT) do { \
    GLDS16(A + rA + (size_t)((H)*128) * Ks + (size_t)(KT)*64,      sdA + (D)*65536 + (H)*16384); \
    GLDS16(A + rA + (size_t)((H)*128 + 64) * Ks + (size_t)(KT)*64, sdA + (D)*65536 + (H)*16384 + 8192); } while (0)
#define STG_B(D, H, KT) do { \
    GLDS16(Bp + rB + (size_t)((H)*128) * Ks + (size_t)(KT)*64,      sdB + (D)*65536 + (H)*16384); \
    GLDS16(Bp + rB + (size_t)((H)*128 + 64) * Ks + (size_t)(KT)*64, sdB + (D)*65536 + (H)*16384 + 8192); } while (0)

  const int sw = (qi & 7) << 4;
  const char* frA = smem + (wm * 128 + qi) * 128;
  const char* frB = smem + 32768 + (wn * 64 + qi) * 128;

#define RDA4(D, F0) do { _Pragma("unroll") for (int f_ = 0; f_ < 4; ++f_) \
    _Pragma("unroll") for (int k_ = 0; k_ < 2; ++k_) \
      a[(F0) + f_][k_] = *(const s8v*)(frA + (D)*65536 + ((F0) + f_) * 2048 + (((k_ << 6) + (g << 4)) ^ sw)); } while (0)
#define RDB2(D, N0) do { _Pragma("unroll") for (int n_ = 0; n_ < 2; ++n_) \
    _Pragma("unroll") for (int k_ = 0; k_ < 2; ++k_) \
      b[(N0) + n_][k_] = *(const s8v*)(frB + (D)*65536 + ((N0) + n_) * 2048 + (((k_ << 6) + (g << 4)) ^ sw)); } while (0)
#define MQUAD(F0, N0) do { __builtin_amdgcn_s_setprio(1); \
    _Pragma("unroll") for (int f_ = 0; f_ < 4; ++f_) \
    _Pragma("unroll") for (int n_ = 0; n_ < 2; ++n_) \
    _Pragma("unroll") for (int k_ = 0; k_ < 2; ++k_) \
      mfma32(acc[(F0) + f_][(N0) + n_], a[(F0) + f_][k_], b[(N0) + n_][k_]); \
    __builtin_amdgcn_s_setprio(0); } while (0)

  f4v acc[8][4];
#pragma unroll
  for (int i = 0; i < 8; ++i)
#pragma unroll
    for (int j = 0; j < 4; ++j) acc[i][j] = (f4v)0.0f;

  STG_A(0, 0, 0); STG_A(0, 1, 0); STG_B(0, 0, 0); STG_B(0, 1, 0);
  STG_A(1, 0, 1); STG_A(1, 1, 1); STG_B(1, 0, 1); STG_B(1, 1, 1);
  WVM8;
  BAR;

  s8v a[8][2], b[4][2];
#pragma unroll 1
  for (int it = 0; it < NT / 2; ++it) {
    const int t = 2 * it;
    const int k2 = (t + 2 < NT) ? t + 2 : NT - 1;
    const int k3 = (t + 3 < NT) ? t + 3 : NT - 1;
    RDA4(0, 0); RDB2(0, 0);
    WLGKM; MQUAD(0, 0); BAR;
    RDB2(0, 2);
    WLGKM; MQUAD(0, 2); BAR;
    RDA4(0, 4);
    STG_B(0, 0, k2); STG_B(0, 1, k2);
    WLGKM; MQUAD(4, 0); BAR;
    STG_A(0, 0, k2); STG_A(0, 1, k2);
    MQUAD(4, 2);
    WVM8; BAR;
    RDA4(1, 0); RDB2(1, 0);
    WLGKM; MQUAD(0, 0); BAR;
    RDB2(1, 2);
    WLGKM; MQUAD(0, 2); BAR;
    RDA4(1, 4);
    STG_B(1, 0, k3); STG_B(1, 1, k3);
    WLGKM; MQUAD(4, 0); BAR;
    STG_A(1, 0, k3); STG_A(1, 1, k3);
    MQUAD(4, 2);
    WVM8; BAR;
  }

  asm volatile("s_waitcnt vmcnt(0)" ::: "memory");
  asm volatile("s_nop 7\n\ts_nop 7" ::: "memory");
  const int r4 = g * 4;
  if (OUTB) {
    unsigned short* Cb = (unsigned short*)Cout + (size_t)half * M * N;
#pragma unroll
    for (int fm = 0; fm < 8; ++fm)
#pragma unroll
      for (int fn = 0; fn < 4; ++fn)
#pragma unroll
        for (int r = 0; r < 4; ++r)
          Cb[(size_t)(m0 + wm * 128 + fm * 16 + r4 + r) * N + (n0 + wn * 64 + fn * 16 + qi)] =
              f2b(acc[fm][fn][r]);
  } else {
    float* Cf = (float*)Cout;
#pragma unroll
    for (int fm = 0; fm < 8; ++fm)
#pragma unroll
      for (int fn = 0; fn < 4; ++fn)
#pragma unroll
        for (int r = 0; r < 4; ++r)
          Cf[(size_t)(m0 + wm * 128 + fm * 16 + r4 + r) * N + (n0 + wn * 64 + fn * 16 + qi)] =
              acc[fm][fn][r];
  }
}

// ---------------------------------------------------------------------------
// Causal GQA flash attention — 4-wave blocks, 2 blocks/CU, single-barrier
// tile, V staged early (full-tile slack), in-place softmax.
// (unchanged from round 17; LDS-port-bound floor for this decomposition)
// ---------------------------------------------------------------------------
__global__ __launch_bounds__(256, 2) void attn_fwd(
    const unsigned short* __restrict__ qb, const unsigned short* __restrict__ kb,
    const unsigned short* __restrict__ vb, unsigned short* __restrict__ ao) {
  __shared__ __align__(16) char smem[81920];
  const int tid = threadIdx.x, lane = tid & 63, wv = tid >> 6;   // wv 0..3
  const int q31 = lane & 31, hi = lane >> 5;
  const int qtb = 15 - blockIdx.x;             // long blocks launch first
  const int h = blockIdx.y, b = blockIdx.z, kvh = h >> 2;
  const int q0 = qtb * 128;
  const int qrow = q0 + wv * 32 + q31;

  s8v qf[8];
  {
    const unsigned short* qp = qb + (size_t)(b * 2048 + qrow) * 4096 + h * 128 + hi * 8;
#pragma unroll
    for (int c = 0; c < 8; ++c) qf[c] = *(const s8v*)(qp + c * 16);
  }

  f16v oacc[4];
#pragma unroll
  for (int i = 0; i < 4; ++i) oacc[i] = (f16v)0.0f;
  float m_run = -3.0e38f, l_run = 0.0f;

  const unsigned short* ksrc[4]; int kdo[4];
#pragma unroll
  for (int j = 0; j < 4; ++j) {
    const int r = wv * 16 + j * 4 + (lane >> 4);
    ksrc[j] = kb + (size_t)(b * 2048 + r) * 1024 + kvh * 128 + (((lane & 15) ^ (r & 15)) << 3);
    kdo[j] = (wv * 16 + j * 4) * 256;
  }
  const unsigned short* vsrc[4]; int vdo[4];
#pragma unroll
  for (int j = 0; j < 4; ++j) {
    const int key = wv * 16 + j * 4 + ((lane & 7) >> 1);
    const int d = ((lane >> 3) & 7) * 16 + (lane & 1) * 8;
    vsrc[j] = vb + (size_t)(b * 2048 + key) * 1024 + kvh * 128 + d;
    vdo[j] = (wv * 32 + j * 8) * 128;
  }

  const int ntiles = 2 * qtb + 2;
  const int my_qmax = q0 + wv * 32 + 31, wq_lo = q0 + wv * 32;

  {
    char* k0d = smem;
    char* k1d = smem + 16384;
    char* v0d = smem + 49152;
#pragma unroll
    for (int j = 0; j < 4; ++j) GLDS16(ksrc[j], k0d + kdo[j]);
#pragma unroll
    for (int j = 0; j < 4; ++j) GLDS16(ksrc[j] + 65536, k1d + kdo[j]);
#pragma unroll
    for (int j = 0; j < 4; ++j) GLDS16(vsrc[j], v0d + vdo[j]);
  }
  asm volatile("s_waitcnt vmcnt(8)" ::: "memory");
  __builtin_amdgcn_sched_barrier(0);
  BAR;

  int kc = 0;
  for (int t = 0; t < ntiles; ++t) {
    const int k0 = t * 64;
    const bool live = (k0 <= my_qmax);
    const char* Kbase = smem + kc * 16384;
    f16v s32a = (f16v)0.0f, s32b = (f16v)0.0f;
    if (live) {
      __builtin_amdgcn_s_setprio(1);
#pragma unroll
      for (int c = 0; c < 8; ++c) {
        const int sl = ((2 * c + hi) ^ (q31 & 15)) << 4;
        s8v kfa = *(const s8v*)(Kbase + q31 * 256 + sl);
        s8v kfb = *(const s8v*)(Kbase + (32 + q31) * 256 + sl);
        mfma3216(s32a, kfa, qf[c]);
        mfma3216(s32b, kfb, qf[c]);
      }
      __builtin_amdgcn_s_setprio(0);
      asm volatile("s_nop 7\n\ts_nop 7\n\ts_nop 7" : "+v"(s32a), "+v"(s32b));
    }
    {                                          // stage K(t+2) -> slot (kc+2)%3
      const int kt2 = (t + 2 < ntiles) ? t + 2 : ntiles - 1;
      char* kd = smem + ((kc >= 1) ? kc - 1 : 2) * 16384;
#pragma unroll
      for (int j = 0; j < 4; ++j) GLDS16(ksrc[j] + (size_t)kt2 * 65536, kd + kdo[j]);
    }
    asm volatile("s_waitcnt vmcnt(4)" ::: "memory");  // drains K(t+1), V(t)
    __builtin_amdgcn_sched_barrier(0);
    BAR;                                       // single barrier per tile
    {                                          // stage V(t+1) EARLY: full-tile slack
      const int vt1 = (t + 1 < ntiles) ? t + 1 : ntiles - 1;
      char* vd = smem + 49152 + ((t + 1) & 1) * 16384;
#pragma unroll
      for (int j = 0; j < 4; ++j) GLDS16(vsrc[j] + (size_t)vt1 * 65536, vd + vdo[j]);
    }
    if (live) {
      const char* vbt = smem + 49152 + (t & 1) * 16384 + hi * 2048 +
                        ((lane >> 4) & 1) * 128 + ((lane & 15) << 3);
      s4v tA[8], tB[8];
#pragma unroll
      for (int u = 0; u < 8; ++u) tA[u] = tr_read(vbt, (u >> 1) * 256 + (u & 1) * 1024);

      // ---- softmax fully in place on s32a/s32b
      float tm = -3.0e38f;
      if (k0 + 64 <= wq_lo) {                  // fully unmasked (Q pre-scaled)
#pragma unroll
        for (int r = 0; r < 16; ++r) {
          tm = fmaxf(tm, s32a[r]);
          tm = fmaxf(tm, s32b[r]);
        }
      } else {                                 // diagonal/partial tile
#pragma unroll
        for (int r = 0; r < 16; ++r) {
          const int kga = k0 + (r & 3) + 8 * ((r >> 2) & 3) + 4 * hi;
          s32a[r] = (kga <= qrow) ? s32a[r] : -3.0e38f;
          tm = fmaxf(tm, s32a[r]);
          const int kgb = kga + 32;
          s32b[r] = (kgb <= qrow) ? s32b[r] : -3.0e38f;
          tm = fmaxf(tm, s32b[r]);
        }
      }
      tm = fmaxf(tm, __shfl_xor(tm, 32));

      if (!__all(tm - m_run <= 8.0f)) {        // T13 defer-max
        const float m_new = fmaxf(m_run, tm);
        const float al = exp2f(m_run - m_new);
#pragma unroll
        for (int i = 0; i < 4; ++i)
#pragma unroll
          for (int r = 0; r < 16; ++r) oacc[i][r] *= al;
        l_run *= al;
        m_run = m_new;
      }
      float ps = 0.0f;
#pragma unroll
      for (int r = 0; r < 16; ++r) {
        s32a[r] = exp2f(s32a[r] - m_run); ps += s32a[r];
        s32b[r] = exp2f(s32b[r] - m_run); ps += s32b[r];
      }
      ps += __shfl_xor(ps, 32);
      l_run += ps;

      // ---- P -> bf16 B-frags from s32a/s32b (literal-constant indices)
      s8v pf[4];
#define PFMAKE(KS, V, O) do { unsigned c0, c1, c2, c3; \
        asm("v_cvt_pk_bf16_f32 %0, %1, %2" : "=v"(c0) : "v"(V[(O)+0]), "v"(V[(O)+1])); \
        asm("v_cvt_pk_bf16_f32 %0, %1, %2" : "=v"(c1) : "v"(V[(O)+2]), "v"(V[(O)+3])); \
        asm("v_cvt_pk_bf16_f32 %0, %1, %2" : "=v"(c2) : "v"(V[(O)+4]), "v"(V[(O)+5])); \
        asm("v_cvt_pk_bf16_f32 %0, %1, %2" : "=v"(c3) : "v"(V[(O)+6]), "v"(V[(O)+7])); \
        asm volatile("v_permlane32_swap_b32 %0, %1" : "+v"(c0), "+v"(c2)); \
        asm volatile("v_permlane32_swap_b32 %0, %1" : "+v"(c1), "+v"(c3)); \
        u4v pw; pw.x = c0; pw.y = c1; pw.z = c2; pw.w = c3; \
        pf[KS] = __builtin_bit_cast(s8v, pw); } while (0)
      PFMAKE(0, s32a, 0);
      PFMAKE(1, s32a, 8);
      PFMAKE(2, s32b, 0);
      PFMAKE(3, s32b, 8);
#undef PFMAKE

#define PVS(KS, CUR, NXT, LAST) do { \
        if (!(LAST)) { \
          _Pragma("unroll") for (int u = 0; u < 8; ++u) \
            NXT[u] = tr_read(vbt, ((KS)+1)*4096 + (u >> 1) * 256 + (u & 1) * 1024); \
          asm volatile("s_waitcnt lgkmcnt(8)" ::: "memory"); \
        } else { asm volatile("s_waitcnt lgkmcnt(0)" ::: "memory"); } \
        __builtin_amdgcn_sched_barrier(0); \
        __builtin_amdgcn_s_setprio(1); \
        _Pragma("unroll") for (int dt = 0; dt < 4; ++dt) { \
          s8v vf = __builtin_shufflevector(CUR[dt*2], CUR[dt*2+1], 0,1,2,3,4,5,6,7); \
          mfma3216(oacc[dt], vf, pf[KS]); } \
        __builtin_amdgcn_s_setprio(0); \
      } while (0)
      PVS(0, tA, tB, 0);
      PVS(1, tB, tA, 0);
      PVS(2, tA, tB, 0);
      PVS(3, tB, tA, 1);
#undef PVS
    }
    kc = (kc == 2) ? 0 : kc + 1;
  }

  // ---- epilogue: O -> swizzled f32 LDS (2 passes of 2 waves) -> bf16 stores
  asm volatile("s_waitcnt vmcnt(0) lgkmcnt(0)" ::: "memory");
  asm volatile("s_nop 7\n\ts_nop 7\n\ts_nop 7" ::: "memory");
  __syncthreads();
  const float inv = 1.0f / l_run;
  float* Ost = (float*)smem;
  const int er = tid >> 2, ew = (tid & 3) * 32;
#pragma unroll
  for (int p = 0; p < 2; ++p) {
    if ((wv >> 1) == p) {
      const int qip = (wv & 1) * 32 + q31;
#pragma unroll
      for (int dt = 0; dt < 4; ++dt)
#pragma unroll
        for (int r = 0; r < 16; ++r) {
          const int d = dt * 32 + (r & 3) + 8 * ((r >> 2) & 3) + 4 * hi;
          Ost[qip * 128 + (d ^ ((qip & 7) << 2))] = oacc[dt][r] * inv;
        }
    }
    __syncthreads();
    const int sw = (er & 7) << 2;
    f4v av[8];
#pragma unroll
    for (int c = 0; c < 8; ++c)
      av[c] = *(const f4v*)(Ost + er * 128 + ((ew + c * 4) ^ sw));
    u4v r0, r1;
    r0.x = pk2(av[0][0], av[0][1]); r0.y = pk2(av[0][2], av[0][3]);
    r0.z = pk2(av[1][0], av[1][1]); r0.w = pk2(av[1][2], av[1][3]);
    r1.x = pk2(av[2][0], av[2][1]); r1.y = pk2(av[2][2], av[2][3]);
    r1.z = pk2(av[3][0], av[3][1]); r1.w = pk2(av[3][2], av[3][3]);
    u4v r2, r3;
    r2.x = pk2(av[4][0], av[4][1]); r2.y = pk2(av[4][2], av[4][3]);
    r2.z = pk2(av[5][0], av[5][1]); r2.w = pk2(av[5][2], av[5][3]);
    r3.x = pk2(av[6][0], av[6][1]); r3.y = pk2(av[6][2], av[6][3]);
    r3.z = pk2(av[7][0], av[7][1]); r3.w = pk2(av[7][2], av[7][3]);
    unsigned short* dst = ao + (size_t)(b * 2048 + q0 + p * 64 + er) * 4096 + h * 128 + ew;
    *(u4v*)dst = r0;
    *(u4v*)(dst + 8) = r1;
    *(u4v*)(dst + 16) = r2;
    *(u4v*)(dst + 24) = r3;
    __syncthreads();
  }
}

// ---------------------------------------------------------------------------
// Host launcher. Workspace (needs ws_size >= 268,435,456 B):
//   [0,32M)     xb bf16        [32M,80M)   wqkv bf16
//   [80M,112M)  wo bf16        [112M,145.5M) attn_out bf16 (aob)
//   [208M,240M) q bf16         [240M,248M) k bf16    [248M,256M) v bf16
// ---------------------------------------------------------------------------
extern "C" void kernel_launch(void* const* d_in, const int* in_sizes, int n_in,
                              void* d_out, int out_size, void* d_ws, size_t ws_size,
                              hipStream_t stream) {
  (void)in_sizes; (void)n_in; (void)out_size; (void)ws_size;
  const float* x  = (const float*)d_in[0];
  const float* wq = (const float*)d_in[1];
  const float* wk = (const float*)d_in[2];
  const float* wv = (const float*)d_in[3];
  const float* wo = (const float*)d_in[4];
  const float* fr = (const float*)d_in[5];
  const float* fi = (const float*)d_in[6];

  float* out = (float*)d_out;
  float* xk  = out + 16777216;
  float* xv  = xk + 4194304;

  char* ws = (char*)d_ws;
  unsigned short* xb    = (unsigned short*)(ws);
  unsigned short* wqkvb = (unsigned short*)(ws + 33554432);
  unsigned short* wob   = (unsigned short*)(ws + 83886080);
  unsigned short* aob   = (unsigned short*)(ws + 117440512);  // 33.5MB bf16
  unsigned short* qbuf  = (unsigned short*)(ws + 218103808);
  unsigned short* kbuf  = (unsigned short*)(ws + 251658240);
  unsigned short* vbuf  = (unsigned short*)(ws + 260046848);

  cvt_bf16<<<16384, 256, 0, stream>>>(x,  xb, 4194304);
  cvt_bf16<<<16384, 256, 0, stream>>>(wq, wqkvb, 4194304);
  cvt_bf16<<<4096,  256, 0, stream>>>(wk, wqkvb + 16777216, 1048576);
  cvt_bf16<<<4096,  256, 0, stream>>>(wv, wqkvb + 20971520, 1048576);
  cvt_bf16<<<16384, 256, 0, stream>>>(wo, wob, 4194304);

  // qkv GEMM with fused RoPE epilogue: 512 blocks = 2 exact rounds
  gemm_qkv<<<512, 512, 0, stream>>>(xb, wqkvb, fr, fi, qbuf, kbuf, vbuf, xk, xv);
  attn_fwd<<<dim3(16, 32, 2), 256, 0, stream>>>(qbuf, kbuf, vbuf, aob);
  gemm_bt8<0><<<256, 512, 0, stream>>>(aob, wob, out, 4096, 4096, 4096, 4096, 256);
}

// Round 19
// 563.529 us; speedup vs baseline: 1.0065x; 1.0065x over previous
//
#include <hip/hip_runtime.h>
#include <hip/hip_bf16.h>

// ---------------------------------------------------------------------------
// Attention block: B=2 S=2048 D=4096 H=32 KV=8 HD=128 (GQA N_REP=4, causal)
// Pipeline: cvt -> GEMM-qkv(256x192, no split) -> RoPE/scatter
//           -> flash-attn(4-wave, 2 blocks/CU) -> GEMM8-256sq(out)
// (Round 19 = revert to round-17 configuration: RoPE-fusion was net negative,
//  separate coalesced rope pass is faster than the scattered fused epilogue.)
// ---------------------------------------------------------------------------

typedef __attribute__((ext_vector_type(8)))  short s8v;   // 8 x bf16 (4 VGPR)
typedef __attribute__((ext_vector_type(4)))  short s4v;   // 4 x bf16 (2 VGPR)
typedef __attribute__((ext_vector_type(4)))  float f4v;
typedef __attribute__((ext_vector_type(16))) float f16v;  // 32x32 MFMA acc
typedef __attribute__((ext_vector_type(2)))  float f2v;
typedef __attribute__((ext_vector_type(2))) unsigned int u2v;
typedef __attribute__((ext_vector_type(4))) unsigned int u4v;

typedef __attribute__((address_space(3))) void lds_void;
typedef __attribute__((address_space(1))) void g_void;

#define GLDS16(gp, lp) __builtin_amdgcn_global_load_lds((g_void*)(gp), (lds_void*)(lp), 16, 0, 0)

#define SCL_LOG2 0.12751744f   // (1/sqrt(128)) * log2(e); pre-folded into Q at rope

__device__ __forceinline__ unsigned short f2b(float f) {  // f32 -> bf16 RNE
  unsigned u = __builtin_bit_cast(unsigned, f);
  u += 0x7fffu + ((u >> 16) & 1u);
  return (unsigned short)(u >> 16);
}
__device__ __forceinline__ unsigned pk2(float a, float b) {
  return (unsigned)f2b(a) | ((unsigned)f2b(b) << 16);
}
__device__ __forceinline__ float b2f(unsigned short h) {
  return __builtin_bit_cast(float, (unsigned)h << 16);
}

// inline-asm MFMAs (volatile; s_nop guards at every MFMA->VALU read-back)
__device__ __forceinline__ void mfma32(f4v& d, s8v a, s8v b) {
  asm volatile("v_mfma_f32_16x16x32_bf16 %0, %1, %2, %0" : "+v"(d) : "v"(a), "v"(b));
}
__device__ __forceinline__ void mfma3216(f16v& d, s8v a, s8v b) {
  asm volatile("v_mfma_f32_32x32x16_bf16 %0, %1, %2, %0" : "+v"(d) : "v"(a), "v"(b));
}
__device__ __forceinline__ s4v tr_read(const char* p, int imm) {
  s4v r;
  asm volatile("ds_read_b64_tr_b16 %0, %1 offset:%2"
               : "=v"(r) : "v"((lds_void*)p), "n"(imm));
  return r;
}

// ---------------------------------------------------------------------------
// f32 -> bf16 convert
// ---------------------------------------------------------------------------
__global__ __launch_bounds__(256) void cvt_bf16(const float* __restrict__ s,
                                                unsigned short* __restrict__ d, int n4) {
  const int i = blockIdx.x * 256 + threadIdx.x;
  if (i >= n4) return;
  f4v v = *(const f4v*)(s + (size_t)i * 4);
  u2v r;
  r.x = pk2(v[0], v[1]);
  r.y = pk2(v[2], v[3]);
  *(u2v*)(d + (size_t)i * 4) = r;
}

// ---------------------------------------------------------------------------
// sync macros shared by GEMM kernels
// ---------------------------------------------------------------------------
#define BAR      asm volatile("s_barrier" ::: "memory")
#define WLGKM    do { asm volatile("s_waitcnt lgkmcnt(0)" ::: "memory"); \
                      __builtin_amdgcn_sched_barrier(0); } while (0)
#define WVM8     do { asm volatile("s_waitcnt vmcnt(8)" ::: "memory"); \
                      __builtin_amdgcn_sched_barrier(0); } while (0)
#define WVM7     do { asm volatile("s_waitcnt vmcnt(7)" ::: "memory"); \
                      __builtin_amdgcn_sched_barrier(0); } while (0)

// ---------------------------------------------------------------------------
// qkv GEMM: 256x192 tile, full K=4096, 512 blocks = 2 exact rounds.
// ---------------------------------------------------------------------------
__global__ __launch_bounds__(512, 2) void gemm_qkv(const unsigned short* __restrict__ A,
                                                   const unsigned short* __restrict__ Bp,
                                                   unsigned short* __restrict__ C) {
  __shared__ __align__(16) char smem[114688];
  const int tid = threadIdx.x, lane = tid & 63, wv = tid >> 6;
  const int qi = lane & 15, g = lane >> 4;
  const int wm = wv >> 1, wn = wv & 1;          // 4M x 2N
  const int K = 4096, N = 6144, NT = 64;

  const int id = blockIdx.x;
  const int swz = (id & 7) * 64 + (id >> 3);
  const int m0 = (swz & 15) * 256, n0 = (swz >> 4) * 192;

  const int srowo = wv * 8 + (lane >> 3);
  const int scole = ((lane & 7) ^ (lane >> 3)) << 3;
  const size_t rA = (size_t)(m0 + srowo) * K + scole;
  const size_t rB = (size_t)(n0 + srowo) * K + scole;
  char* sdA = smem + wv * 1024;
  char* sdB = smem + 65536 + wv * 1024;

#define QSTG_A(D, KT) do { _Pragma("unroll") for (int c_ = 0; c_ < 4; ++c_) \
    GLDS16(A + rA + (size_t)(c_ * 64) * K + (size_t)(KT) * 64, \
           sdA + (D) * 32768 + c_ * 8192); } while (0)
#define QSTG_B(D, KT) do { _Pragma("unroll") for (int c_ = 0; c_ < 3; ++c_) \
    GLDS16(Bp + rB + (size_t)(c_ * 64) * K + (size_t)(KT) * 64, \
           sdB + (D) * 24576 + c_ * 8192); } while (0)

  const int sw = (qi & 7) << 4;
  const char* frA = smem + (wm * 64 + qi) * 128;
  const char* frB = smem + 65536 + (wn * 96 + qi) * 128;

#define QRDA(D, F0) do { _Pragma("unroll") for (int f_ = 0; f_ < 2; ++f_) \
    _Pragma("unroll") for (int k_ = 0; k_ < 2; ++k_) \
      a[(F0) + f_][k_] = *(const s8v*)(frA + (D) * 32768 + ((F0) + f_) * 2048 + (((k_ << 6) + (g << 4)) ^ sw)); } while (0)
#define QRDB(D, N0) do { _Pragma("unroll") for (int n_ = 0; n_ < 3; ++n_) \
    _Pragma("unroll") for (int k_ = 0; k_ < 2; ++k_) \
      b[(N0) + n_][k_] = *(const s8v*)(frB + (D) * 24576 + ((N0) + n_) * 2048 + (((k_ << 6) + (g << 4)) ^ sw)); } while (0)
#define QMQUAD(F0, N0) do { __builtin_amdgcn_s_setprio(1); \
    _Pragma("unroll") for (int f_ = 0; f_ < 2; ++f_) \
    _Pragma("unroll") for (int n_ = 0; n_ < 3; ++n_) \
    _Pragma("unroll") for (int k_ = 0; k_ < 2; ++k_) \
      mfma32(acc[(F0) + f_][(N0) + n_], a[(F0) + f_][k_], b[(N0) + n_][k_]); \
    __builtin_amdgcn_s_setprio(0); } while (0)

  f4v acc[4][6];
#pragma unroll
  for (int i = 0; i < 4; ++i)
#pragma unroll
    for (int j = 0; j < 6; ++j) acc[i][j] = (f4v)0.0f;

  QSTG_A(0, 0); QSTG_B(0, 0);
  QSTG_A(1, 1); QSTG_B(1, 1);
  WVM7;
  BAR;

  s8v a[4][2], b[6][2];
#pragma unroll 1
  for (int it = 0; it < NT / 2; ++it) {
    const int t = 2 * it;
    const int k2 = (t + 2 < NT) ? t + 2 : NT - 1;
    const int k3 = (t + 3 < NT) ? t + 3 : NT - 1;
    QRDA(0, 0); QRDB(0, 0);
    WLGKM; QMQUAD(0, 0); BAR;
    QRDB(0, 3);
    WLGKM; QMQUAD(0, 3); BAR;
    QRDA(0, 2);
    QSTG_B(0, k2);
    WLGKM; QMQUAD(2, 0); BAR;
    QSTG_A(0, k2);
    QMQUAD(2, 3);
    WVM7; BAR;
    QRDA(1, 0); QRDB(1, 0);
    WLGKM; QMQUAD(0, 0); BAR;
    QRDB(1, 3);
    WLGKM; QMQUAD(0, 3); BAR;
    QRDA(1, 2);
    QSTG_B(1, k3);
    WLGKM; QMQUAD(2, 0); BAR;
    QSTG_A(1, k3);
    QMQUAD(2, 3);
    WVM7; BAR;
  }

  asm volatile("s_waitcnt vmcnt(0)" ::: "memory");
  asm volatile("s_nop 7\n\ts_nop 7" ::: "memory");
  const int r4 = g * 4;
#pragma unroll
  for (int fm = 0; fm < 4; ++fm)
#pragma unroll
    for (int fn = 0; fn < 6; ++fn)
#pragma unroll
      for (int r = 0; r < 4; ++r)
        C[(size_t)(m0 + wm * 64 + fm * 16 + r4 + r) * N + (n0 + wn * 96 + fn * 16 + qi)] =
            f2b(acc[fm][fn][r]);
}

// ---------------------------------------------------------------------------
// 8-phase 256-sq GEMM (round-10 schedule v3, proven) — used for out-proj.
// ---------------------------------------------------------------------------
template <int OUTB>
__global__ __launch_bounds__(512, 2) void gemm_bt8(const unsigned short* __restrict__ A,
                                                   const unsigned short* __restrict__ Bp,
                                                   void* __restrict__ Cout,
                                                   int M, int N, int Ks, int Klen,
                                                   int nTiles) {
  __shared__ __align__(16) char smem[131072];
  const int tid = threadIdx.x, lane = tid & 63, wv = tid >> 6;
  const int qi = lane & 15, g = lane >> 4;
  const int wm = wv >> 2, wn = wv & 3;

  const int nwg = gridDim.x, cpx = nwg >> 3;
  const int id = blockIdx.x;
  const int swz = (id & 7) * cpx + (id >> 3);
  const int half = swz / nTiles;
  const int tile = swz - half * nTiles;
  const int kOff = half * Klen;
  const int MT = M >> 8;
  const int m0 = (tile % MT) * 256, n0 = (tile / MT) * 256;
  const int NT = Klen >> 6;

  const int srowo = wv * 8 + (lane >> 3);
  const int scole = ((lane & 7) ^ (lane >> 3)) << 3;
  const size_t rA = (size_t)(m0 + srowo) * Ks + kOff + scole;
  const size_t rB = (size_t)(n0 + srowo) * Ks + kOff + scole;
  char* sdA = smem + wv * 1024;
  char* sdB = smem + 32768 + wv * 1024;

#define STG_A(D, H, KT) do { \
    GLDS16(A + rA + (size_t)((H)*128) * Ks + (size_t)(KT)*64,      sdA + (D)*65536 + (H)*16384); \
    GLDS16(A + rA + (size_t)((H)*128 + 64) * Ks + (size_t)(KT)*64, sdA + (D)*65536 + (H)*16384 + 8192); } while (0)
#define STG_B(D, H, KT) do { \
    GLDS16(Bp + rB + (size_t)((H)*128) * Ks + (size_t)(KT)*64,      sdB + (D)*65536 + (H)*16384); \
    GLDS16(Bp + rB + (size_t)((H)*128 + 64) * Ks + (size_t)(KT)*64, sdB + (D)*65536 + (H)*16384 + 8192); } while (0)

  const int sw = (qi & 7) << 4;
  const char* frA = smem + (wm * 128 + qi) * 128;
  const char* frB = smem + 32768 + (wn * 64 + qi) * 128;

#define RDA4(D, F0) do { _Pragma("unroll") for (int f_ = 0; f_ < 4; ++f_) \
    _Pragma("unroll") for (int k_ = 0; k_ < 2; ++k_) \
      a[(F0) + f_][k_] = *(const s8v*)(frA + (D)*65536 + ((F0) + f_) * 2048 + (((k_ << 6) + (g << 4)) ^ sw)); } while (0)
#define RDB2(D, N0) do { _Pragma("unroll") for (int n_ = 0; n_ < 2; ++n_) \
    _Pragma("unroll") for (int k_ = 0; k_ < 2; ++k_) \
      b[(N0) + n_][k_] = *(const s8v*)(frB + (D)*65536 + ((N0) + n_) * 2048 + (((k_ << 6) + (g << 4)) ^ sw)); } while (0)
#define MQUAD(F0, N0) do { __builtin_amdgcn_s_setprio(1); \
    _Pragma("unroll") for (int f_ = 0; f_ < 4; ++f_) \
    _Pragma("unroll") for (int n_ = 0; n_ < 2; ++n_) \
    _Pragma("unroll") for (int k_ = 0; k_ < 2; ++k_) \
      mfma32(acc[(F0) + f_][(N0) + n_], a[(F0) + f_][k_], b[(N0) + n_][k_]); \
    __builtin_amdgcn_s_setprio(0); } while (0)

  f4v acc[8][4];
#pragma unroll
  for (int i = 0; i < 8; ++i)
#pragma unroll
    for (int j = 0; j < 4; ++j) acc[i][j] = (f4v)0.0f;

  STG_A(0, 0, 0); STG_A(0, 1, 0); STG_B(0, 0, 0); STG_B(0, 1, 0);
  STG_A(1, 0, 1); STG_A(1, 1, 1); STG_B(1, 0, 1); STG_B(1, 1, 1);
  WVM8;
  BAR;

  s8v a[8][2], b[4][2];
#pragma unroll 1
  for (int it = 0; it < NT / 2; ++it) {
    const int t = 2 * it;
    const int k2 = (t + 2 < NT) ? t + 2 : NT - 1;
    const int k3 = (t + 3 < NT) ? t + 3 : NT - 1;
    RDA4(0, 0); RDB2(0, 0);
    WLGKM; MQUAD(0, 0); BAR;
    RDB2(0, 2);
    WLGKM; MQUAD(0, 2); BAR;
    RDA4(0, 4);
    STG_B(0, 0, k2); STG_B(0, 1, k2);
    WLGKM; MQUAD(4, 0); BAR;
    STG_A(0, 0, k2); STG_A(0, 1, k2);
    MQUAD(4, 2);
    WVM8; BAR;
    RDA4(1, 0); RDB2(1, 0);
    WLGKM; MQUAD(0, 0); BAR;
    RDB2(1, 2);
    WLGKM; MQUAD(0, 2); BAR;
    RDA4(1, 4);
    STG_B(1, 0, k3); STG_B(1, 1, k3);
    WLGKM; MQUAD(4, 0); BAR;
    STG_A(1, 0, k3); STG_A(1, 1, k3);
    MQUAD(4, 2);
    WVM8; BAR;
  }

  asm volatile("s_waitcnt vmcnt(0)" ::: "memory");
  asm volatile("s_nop 7\n\ts_nop 7" ::: "memory");
  const int r4 = g * 4;
  if (OUTB) {
    unsigned short* Cb = (unsigned short*)Cout + (size_t)half * M * N;
#pragma unroll
    for (int fm = 0; fm < 8; ++fm)
#pragma unroll
      for (int fn = 0; fn < 4; ++fn)
#pragma unroll
        for (int r = 0; r < 4; ++r)
          Cb[(size_t)(m0 + wm * 128 + fm * 16 + r4 + r) * N + (n0 + wn * 64 + fn * 16 + qi)] =
              f2b(acc[fm][fn][r]);
  } else {
    float* Cf = (float*)Cout;
#pragma unroll
    for (int fm = 0; fm < 8; ++fm)
#pragma unroll
      for (int fn = 0; fn < 4; ++fn)
#pragma unroll
        for (int r = 0; r < 4; ++r)
          Cf[(size_t)(m0 + wm * 128 + fm * 16 + r4 + r) * N + (n0 + wn * 64 + fn * 16 + qi)] =
              acc[fm][fn][r];
  }
}

// ---------------------------------------------------------------------------
// RoPE + scatter (coalesced separate pass; single qkv buffer, Q pre-scaled)
// ---------------------------------------------------------------------------
__global__ __launch_bounds__(256) void rope_scatter(
    const unsigned short* __restrict__ qkvp, const float* __restrict__ fr,
    const float* __restrict__ fi,
    unsigned short* __restrict__ qb, unsigned short* __restrict__ kb,
    unsigned short* __restrict__ vbuf, float* __restrict__ xk, float* __restrict__ xv) {
  const int idx = blockIdx.x * 256 + threadIdx.x;
  const int token = idx / 3072;
  const int col2  = (idx - token * 3072) * 2;
  const int pos   = token & 2047;
  const unsigned u1 = *(const unsigned*)(qkvp + (size_t)token * 6144 + col2);
  float v0 = b2f((unsigned short)u1);
  float v1 = b2f((unsigned short)(u1 >> 16));
  if (col2 < 4096) {
    const int j = (col2 & 127) >> 1;
    const float cr = fr[pos * 64 + j], ci = fi[pos * 64 + j];
    const float a = (v0 * cr - ci * v1) * SCL_LOG2;
    const float o = (v0 * ci + v1 * cr) * SCL_LOG2;
    *(unsigned*)(qb + (size_t)token * 4096 + col2) = pk2(a, o);
  } else if (col2 < 5120) {
    const int lc = col2 - 4096;
    const int j = (lc & 127) >> 1;
    const float cr = fr[pos * 64 + j], ci = fi[pos * 64 + j];
    const float a = v0 * cr - ci * v1;
    const float o = v0 * ci + v1 * cr;
    *(unsigned*)(kb + (size_t)token * 1024 + lc) = pk2(a, o);
    f2v w; w.x = a; w.y = o;
    *(f2v*)(xk + (size_t)token * 1024 + lc) = w;
  } else {
    const int lc = col2 - 5120;
    *(unsigned*)(vbuf + (size_t)token * 1024 + lc) = u1;
    f2v w; w.x = v0; w.y = v1;
    *(f2v*)(xv + (size_t)token * 1024 + lc) = w;
  }
}

// ---------------------------------------------------------------------------
// Causal GQA flash attention — 4-wave blocks, 2 blocks/CU, single-barrier
// tile, V staged early (full-tile slack), in-place softmax.
// (LDS-port-bound floor for this decomposition: predicted MfmaUtil 15.4% ==
//  measured 15.5%.)
// ---------------------------------------------------------------------------
__global__ __launch_bounds__(256, 2) void attn_fwd(
    const unsigned short* __restrict__ qb, const unsigned short* __restrict__ kb,
    const unsigned short* __restrict__ vb, unsigned short* __restrict__ ao) {
  __shared__ __align__(16) char smem[81920];
  const int tid = threadIdx.x, lane = tid & 63, wv = tid >> 6;   // wv 0..3
  const int q31 = lane & 31, hi = lane >> 5;
  const int qtb = 15 - blockIdx.x;             // long blocks launch first
  const int h = blockIdx.y, b = blockIdx.z, kvh = h >> 2;
  const int q0 = qtb * 128;
  const int qrow = q0 + wv * 32 + q31;

  s8v qf[8];
  {
    const unsigned short* qp = qb + (size_t)(b * 2048 + qrow) * 4096 + h * 128 + hi * 8;
#pragma unroll
    for (int c = 0; c < 8; ++c) qf[c] = *(const s8v*)(qp + c * 16);
  }

  f16v oacc[4];
#pragma unroll
  for (int i = 0; i < 4; ++i) oacc[i] = (f16v)0.0f;
  float m_run = -3.0e38f, l_run = 0.0f;

  const unsigned short* ksrc[4]; int kdo[4];
#pragma unroll
  for (int j = 0; j < 4; ++j) {
    const int r = wv * 16 + j * 4 + (lane >> 4);
    ksrc[j] = kb + (size_t)(b * 2048 + r) * 1024 + kvh * 128 + (((lane & 15) ^ (r & 15)) << 3);
    kdo[j] = (wv * 16 + j * 4) * 256;
  }
  const unsigned short* vsrc[4]; int vdo[4];
#pragma unroll
  for (int j = 0; j < 4; ++j) {
    const int key = wv * 16 + j * 4 + ((lane & 7) >> 1);
    const int d = ((lane >> 3) & 7) * 16 + (lane & 1) * 8;
    vsrc[j] = vb + (size_t)(b * 2048 + key) * 1024 + kvh * 128 + d;
    vdo[j] = (wv * 32 + j * 8) * 128;
  }

  const int ntiles = 2 * qtb + 2;
  const int my_qmax = q0 + wv * 32 + 31, wq_lo = q0 + wv * 32;

  {
    char* k0d = smem;
    char* k1d = smem + 16384;
    char* v0d = smem + 49152;
#pragma unroll
    for (int j = 0; j < 4; ++j) GLDS16(ksrc[j], k0d + kdo[j]);
#pragma unroll
    for (int j = 0; j < 4; ++j) GLDS16(ksrc[j] + 65536, k1d + kdo[j]);
#pragma unroll
    for (int j = 0; j < 4; ++j) GLDS16(vsrc[j], v0d + vdo[j]);
  }
  asm volatile("s_waitcnt vmcnt(8)" ::: "memory");
  __builtin_amdgcn_sched_barrier(0);
  BAR;

  int kc = 0;
  for (int t = 0; t < ntiles; ++t) {
    const int k0 = t * 64;
    const bool live = (k0 <= my_qmax);
    const char* Kbase = smem + kc * 16384;
    f16v s32a = (f16v)0.0f, s32b = (f16v)0.0f;
    if (live) {
      __builtin_amdgcn_s_setprio(1);
#pragma unroll
      for (int c = 0; c < 8; ++c) {
        const int sl = ((2 * c + hi) ^ (q31 & 15)) << 4;
        s8v kfa = *(const s8v*)(Kbase + q31 * 256 + sl);
        s8v kfb = *(const s8v*)(Kbase + (32 + q31) * 256 + sl);
        mfma3216(s32a, kfa, qf[c]);
        mfma3216(s32b, kfb, qf[c]);
      }
      __builtin_amdgcn_s_setprio(0);
      asm volatile("s_nop 7\n\ts_nop 7\n\ts_nop 7" : "+v"(s32a), "+v"(s32b));
    }
    {                                          // stage K(t+2) -> slot (kc+2)%3
      const int kt2 = (t + 2 < ntiles) ? t + 2 : ntiles - 1;
      char* kd = smem + ((kc >= 1) ? kc - 1 : 2) * 16384;
#pragma unroll
      for (int j = 0; j < 4; ++j) GLDS16(ksrc[j] + (size_t)kt2 * 65536, kd + kdo[j]);
    }
    asm volatile("s_waitcnt vmcnt(4)" ::: "memory");  // drains K(t+1), V(t)
    __builtin_amdgcn_sched_barrier(0);
    BAR;                                       // single barrier per tile
    {                                          // stage V(t+1) EARLY: full-tile slack
      const int vt1 = (t + 1 < ntiles) ? t + 1 : ntiles - 1;
      char* vd = smem + 49152 + ((t + 1) & 1) * 16384;
#pragma unroll
      for (int j = 0; j < 4; ++j) GLDS16(vsrc[j] + (size_t)vt1 * 65536, vd + vdo[j]);
    }
    if (live) {
      const char* vbt = smem + 49152 + (t & 1) * 16384 + hi * 2048 +
                        ((lane >> 4) & 1) * 128 + ((lane & 15) << 3);
      s4v tA[8], tB[8];
#pragma unroll
      for (int u = 0; u < 8; ++u) tA[u] = tr_read(vbt, (u >> 1) * 256 + (u & 1) * 1024);

      // ---- softmax fully in place on s32a/s32b
      float tm = -3.0e38f;
      if (k0 + 64 <= wq_lo) {                  // fully unmasked (Q pre-scaled)
#pragma unroll
        for (int r = 0; r < 16; ++r) {
          tm = fmaxf(tm, s32a[r]);
          tm = fmaxf(tm, s32b[r]);
        }
      } else {                                 // diagonal/partial tile
#pragma unroll
        for (int r = 0; r < 16; ++r) {
          const int kga = k0 + (r & 3) + 8 * ((r >> 2) & 3) + 4 * hi;
          s32a[r] = (kga <= qrow) ? s32a[r] : -3.0e38f;
          tm = fmaxf(tm, s32a[r]);
          const int kgb = kga + 32;
          s32b[r] = (kgb <= qrow) ? s32b[r] : -3.0e38f;
          tm = fmaxf(tm, s32b[r]);
        }
      }
      tm = fmaxf(tm, __shfl_xor(tm, 32));

      if (!__all(tm - m_run <= 8.0f)) {        // T13 defer-max
        const float m_new = fmaxf(m_run, tm);
        const float al = exp2f(m_run - m_new);
#pragma unroll
        for (int i = 0; i < 4; ++i)
#pragma unroll
          for (int r = 0; r < 16; ++r) oacc[i][r] *= al;
        l_run *= al;
        m_run = m_new;
      }
      float ps = 0.0f;
#pragma unroll
      for (int r = 0; r < 16; ++r) {
        s32a[r] = exp2f(s32a[r] - m_run); ps += s32a[r];
        s32b[r] = exp2f(s32b[r] - m_run); ps += s32b[r];
      }
      ps += __shfl_xor(ps, 32);
      l_run += ps;

      // ---- P -> bf16 B-frags from s32a/s32b (literal-constant indices)
      s8v pf[4];
#define PFMAKE(KS, V, O) do { unsigned c0, c1, c2, c3; \
        asm("v_cvt_pk_bf16_f32 %0, %1, %2" : "=v"(c0) : "v"(V[(O)+0]), "v"(V[(O)+1])); \
        asm("v_cvt_pk_bf16_f32 %0, %1, %2" : "=v"(c1) : "v"(V[(O)+2]), "v"(V[(O)+3])); \
        asm("v_cvt_pk_bf16_f32 %0, %1, %2" : "=v"(c2) : "v"(V[(O)+4]), "v"(V[(O)+5])); \
        asm("v_cvt_pk_bf16_f32 %0, %1, %2" : "=v"(c3) : "v"(V[(O)+6]), "v"(V[(O)+7])); \
        asm volatile("v_permlane32_swap_b32 %0, %1" : "+v"(c0), "+v"(c2)); \
        asm volatile("v_permlane32_swap_b32 %0, %1" : "+v"(c1), "+v"(c3)); \
        u4v pw; pw.x = c0; pw.y = c1; pw.z = c2; pw.w = c3; \
        pf[KS] = __builtin_bit_cast(s8v, pw); } while (0)
      PFMAKE(0, s32a, 0);
      PFMAKE(1, s32a, 8);
      PFMAKE(2, s32b, 0);
      PFMAKE(3, s32b, 8);
#undef PFMAKE

#define PVS(KS, CUR, NXT, LAST) do { \
        if (!(LAST)) { \
          _Pragma("unroll") for (int u = 0; u < 8; ++u) \
            NXT[u] = tr_read(vbt, ((KS)+1)*4096 + (u >> 1) * 256 + (u & 1) * 1024); \
          asm volatile("s_waitcnt lgkmcnt(8)" ::: "memory"); \
        } else { asm volatile("s_waitcnt lgkmcnt(0)" ::: "memory"); } \
        __builtin_amdgcn_sched_barrier(0); \
        __builtin_amdgcn_s_setprio(1); \
        _Pragma("unroll") for (int dt = 0; dt < 4; ++dt) { \
          s8v vf = __builtin_shufflevector(CUR[dt*2], CUR[dt*2+1], 0,1,2,3,4,5,6,7); \
          mfma3216(oacc[dt], vf, pf[KS]); } \
        __builtin_amdgcn_s_setprio(0); \
      } while (0)
      PVS(0, tA, tB, 0);
      PVS(1, tB, tA, 0);
      PVS(2, tA, tB, 0);
      PVS(3, tB, tA, 1);
#undef PVS
    }
    kc = (kc == 2) ? 0 : kc + 1;
  }

  // ---- epilogue: O -> swizzled f32 LDS (2 passes of 2 waves) -> bf16 stores
  asm volatile("s_waitcnt vmcnt(0) lgkmcnt(0)" ::: "memory");
  asm volatile("s_nop 7\n\ts_nop 7\n\ts_nop 7" ::: "memory");
  __syncthreads();
  const float inv = 1.0f / l_run;
  float* Ost = (float*)smem;
  const int er = tid >> 2, ew = (tid & 3) * 32;
#pragma unroll
  for (int p = 0; p < 2; ++p) {
    if ((wv >> 1) == p) {
      const int qip = (wv & 1) * 32 + q31;
#pragma unroll
      for (int dt = 0; dt < 4; ++dt)
#pragma unroll
        for (int r = 0; r < 16; ++r) {
          const int d = dt * 32 + (r & 3) + 8 * ((r >> 2) & 3) + 4 * hi;
          Ost[qip * 128 + (d ^ ((qip & 7) << 2))] = oacc[dt][r] * inv;
        }
    }
    __syncthreads();
    const int sw = (er & 7) << 2;
    f4v av[8];
#pragma unroll
    for (int c = 0; c < 8; ++c)
      av[c] = *(const f4v*)(Ost + er * 128 + ((ew + c * 4) ^ sw));
    u4v r0, r1;
    r0.x = pk2(av[0][0], av[0][1]); r0.y = pk2(av[0][2], av[0][3]);
    r0.z = pk2(av[1][0], av[1][1]); r0.w = pk2(av[1][2], av[1][3]);
    r1.x = pk2(av[2][0], av[2][1]); r1.y = pk2(av[2][2], av[2][3]);
    r1.z = pk2(av[3][0], av[3][1]); r1.w = pk2(av[3][2], av[3][3]);
    u4v r2, r3;
    r2.x = pk2(av[4][0], av[4][1]); r2.y = pk2(av[4][2], av[4][3]);
    r2.z = pk2(av[5][0], av[5][1]); r2.w = pk2(av[5][2], av[5][3]);
    r3.x = pk2(av[6][0], av[6][1]); r3.y = pk2(av[6][2], av[6][3]);
    r3.z = pk2(av[7][0], av[7][1]); r3.w = pk2(av[7][2], av[7][3]);
    unsigned short* dst = ao + (size_t)(b * 2048 + q0 + p * 64 + er) * 4096 + h * 128 + ew;
    *(u4v*)dst = r0;
    *(u4v*)(dst + 8) = r1;
    *(u4v*)(dst + 16) = r2;
    *(u4v*)(dst + 24) = r3;
    __syncthreads();
  }
}

// ---------------------------------------------------------------------------
// Host launcher. Workspace (needs ws_size >= 268,435,456 B):
//   [0,32M)     xb bf16        [32M,80M)   wqkv bf16
//   [80M,112M)  wo bf16        [112M,160M) qkv bf16 single [4096][6144]
//   [160M,193.5M) attn_out bf16 (aob)
//   [208M,240M) q bf16         [240M,248M) k bf16    [248M,256M) v bf16
// ---------------------------------------------------------------------------
extern "C" void kernel_launch(void* const* d_in, const int* in_sizes, int n_in,
                              void* d_out, int out_size, void* d_ws, size_t ws_size,
                              hipStream_t stream) {
  (void)in_sizes; (void)n_in; (void)out_size; (void)ws_size;
  const float* x  = (const float*)d_in[0];
  const float* wq = (const float*)d_in[1];
  const float* wk = (const float*)d_in[2];
  const float* wv = (const float*)d_in[3];
  const float* wo = (const float*)d_in[4];
  const float* fr = (const float*)d_in[5];
  const float* fi = (const float*)d_in[6];

  float* out = (float*)d_out;
  float* xk  = out + 16777216;
  float* xv  = xk + 4194304;

  char* ws = (char*)d_ws;
  unsigned short* xb    = (unsigned short*)(ws);
  unsigned short* wqkvb = (unsigned short*)(ws + 33554432);
  unsigned short* wob   = (unsigned short*)(ws + 83886080);
  unsigned short* qkvb  = (unsigned short*)(ws + 117440512);  // 48MB bf16
  unsigned short* aob   = (unsigned short*)(ws + 167772160);  // 33.5MB bf16
  unsigned short* qbuf  = (unsigned short*)(ws + 218103808);
  unsigned short* kbuf  = (unsigned short*)(ws + 251658240);
  unsigned short* vbuf  = (unsigned short*)(ws + 260046848);

  cvt_bf16<<<16384, 256, 0, stream>>>(x,  xb, 4194304);
  cvt_bf16<<<16384, 256, 0, stream>>>(wq, wqkvb, 4194304);
  cvt_bf16<<<4096,  256, 0, stream>>>(wk, wqkvb + 16777216, 1048576);
  cvt_bf16<<<4096,  256, 0, stream>>>(wv, wqkvb + 20971520, 1048576);
  cvt_bf16<<<16384, 256, 0, stream>>>(wo, wob, 4194304);

  // qkv: 256x192 tiles, full K -> 512 blocks = 2 exact rounds on 256 CUs
  gemm_qkv<<<512, 512, 0, stream>>>(xb, wqkvb, qkvb);
  rope_scatter<<<49152, 256, 0, stream>>>(qkvb, fr, fi, qbuf, kbuf, vbuf, xk, xv);
  attn_fwd<<<dim3(16, 32, 2), 256, 0, stream>>>(qbuf, kbuf, vbuf, aob);
  gemm_bt8<0><<<256, 512, 0, stream>>>(aob, wob, out, 4096, 4096, 4096, 4096, 256);
}

// Round 20
// 547.136 us; speedup vs baseline: 1.0367x; 1.0300x over previous
//
#include <hip/hip_runtime.h>
#include <hip/hip_bf16.h>

// ---------------------------------------------------------------------------
// Attention block: B=2 S=2048 D=4096 H=32 KV=8 HD=128 (GQA N_REP=4, causal)
// Pipeline: cvt_all(1 launch) -> GEMM-qkv(256x192) -> RoPE/scatter
//           -> flash-attn(4-wave, 2 blocks/CU) -> GEMM8-256sq(out)
// Round 20: merge the 5 f32->bf16 convert launches into ONE range-mapped
// kernel (saves 4 dispatch gaps + 4 launch tails; same bytes moved).
// ---------------------------------------------------------------------------

typedef __attribute__((ext_vector_type(8)))  short s8v;   // 8 x bf16 (4 VGPR)
typedef __attribute__((ext_vector_type(4)))  short s4v;   // 4 x bf16 (2 VGPR)
typedef __attribute__((ext_vector_type(4)))  float f4v;
typedef __attribute__((ext_vector_type(16))) float f16v;  // 32x32 MFMA acc
typedef __attribute__((ext_vector_type(2)))  float f2v;
typedef __attribute__((ext_vector_type(2))) unsigned int u2v;
typedef __attribute__((ext_vector_type(4))) unsigned int u4v;

typedef __attribute__((address_space(3))) void lds_void;
typedef __attribute__((address_space(1))) void g_void;

#define GLDS16(gp, lp) __builtin_amdgcn_global_load_lds((g_void*)(gp), (lds_void*)(lp), 16, 0, 0)

#define SCL_LOG2 0.12751744f   // (1/sqrt(128)) * log2(e); pre-folded into Q at rope

__device__ __forceinline__ unsigned short f2b(float f) {  // f32 -> bf16 RNE
  unsigned u = __builtin_bit_cast(unsigned, f);
  u += 0x7fffu + ((u >> 16) & 1u);
  return (unsigned short)(u >> 16);
}
__device__ __forceinline__ unsigned pk2(float a, float b) {
  return (unsigned)f2b(a) | ((unsigned)f2b(b) << 16);
}
__device__ __forceinline__ float b2f(unsigned short h) {
  return __builtin_bit_cast(float, (unsigned)h << 16);
}

// inline-asm MFMAs (volatile; s_nop guards at every MFMA->VALU read-back)
__device__ __forceinline__ void mfma32(f4v& d, s8v a, s8v b) {
  asm volatile("v_mfma_f32_16x16x32_bf16 %0, %1, %2, %0" : "+v"(d) : "v"(a), "v"(b));
}
__device__ __forceinline__ void mfma3216(f16v& d, s8v a, s8v b) {
  asm volatile("v_mfma_f32_32x32x16_bf16 %0, %1, %2, %0" : "+v"(d) : "v"(a), "v"(b));
}
__device__ __forceinline__ s4v tr_read(const char* p, int imm) {
  s4v r;
  asm volatile("ds_read_b64_tr_b16 %0, %1 offset:%2"
               : "=v"(r) : "v"((lds_void*)p), "n"(imm));
  return r;
}

// ---------------------------------------------------------------------------
// Merged f32 -> bf16 convert: one launch covers x|wq|wk|wv|wo.
// f4-unit ranges (exact, grid 57344 x 256 = 14,680,064 threads):
//   x  [0, 4194304)         -> xb
//   wq [4194304, 8388608)   -> wqkvb
//   wk [8388608, 9437184)   -> wqkvb + 16777216
//   wv [9437184, 10485760)  -> wqkvb + 20971520
//   wo [10485760, 14680064) -> wob
// ---------------------------------------------------------------------------
__global__ __launch_bounds__(256) void cvt_all(
    const float* __restrict__ x,  const float* __restrict__ wq,
    const float* __restrict__ wk, const float* __restrict__ wv,
    const float* __restrict__ wo,
    unsigned short* __restrict__ xb, unsigned short* __restrict__ wqkvb,
    unsigned short* __restrict__ wob) {
  const int i = blockIdx.x * 256 + threadIdx.x;
  const float* s;
  unsigned short* d;
  int o;
  if (i < 4194304)        { s = x;  d = xb;              o = i; }
  else if (i < 8388608)   { s = wq; d = wqkvb;           o = i - 4194304; }
  else if (i < 9437184)   { s = wk; d = wqkvb + 16777216; o = i - 8388608; }
  else if (i < 10485760)  { s = wv; d = wqkvb + 20971520; o = i - 9437184; }
  else                    { s = wo; d = wob;             o = i - 10485760; }
  f4v v = *(const f4v*)(s + (size_t)o * 4);
  u2v r;
  r.x = pk2(v[0], v[1]);
  r.y = pk2(v[2], v[3]);
  *(u2v*)(d + (size_t)o * 4) = r;
}

// ---------------------------------------------------------------------------
// sync macros shared by GEMM kernels
// ---------------------------------------------------------------------------
#define BAR      asm volatile("s_barrier" ::: "memory")
#define WLGKM    do { asm volatile("s_waitcnt lgkmcnt(0)" ::: "memory"); \
                      __builtin_amdgcn_sched_barrier(0); } while (0)
#define WVM8     do { asm volatile("s_waitcnt vmcnt(8)" ::: "memory"); \
                      __builtin_amdgcn_sched_barrier(0); } while (0)
#define WVM7     do { asm volatile("s_waitcnt vmcnt(7)" ::: "memory"); \
                      __builtin_amdgcn_sched_barrier(0); } while (0)

// ---------------------------------------------------------------------------
// qkv GEMM: 256x192 tile, full K=4096, 512 blocks = 2 exact rounds.
// ---------------------------------------------------------------------------
__global__ __launch_bounds__(512, 2) void gemm_qkv(const unsigned short* __restrict__ A,
                                                   const unsigned short* __restrict__ Bp,
                                                   unsigned short* __restrict__ C) {
  __shared__ __align__(16) char smem[114688];
  const int tid = threadIdx.x, lane = tid & 63, wv = tid >> 6;
  const int qi = lane & 15, g = lane >> 4;
  const int wm = wv >> 1, wn = wv & 1;          // 4M x 2N
  const int K = 4096, N = 6144, NT = 64;

  const int id = blockIdx.x;
  const int swz = (id & 7) * 64 + (id >> 3);
  const int m0 = (swz & 15) * 256, n0 = (swz >> 4) * 192;

  const int srowo = wv * 8 + (lane >> 3);
  const int scole = ((lane & 7) ^ (lane >> 3)) << 3;
  const size_t rA = (size_t)(m0 + srowo) * K + scole;
  const size_t rB = (size_t)(n0 + srowo) * K + scole;
  char* sdA = smem + wv * 1024;
  char* sdB = smem + 65536 + wv * 1024;

#define QSTG_A(D, KT) do { _Pragma("unroll") for (int c_ = 0; c_ < 4; ++c_) \
    GLDS16(A + rA + (size_t)(c_ * 64) * K + (size_t)(KT) * 64, \
           sdA + (D) * 32768 + c_ * 8192); } while (0)
#define QSTG_B(D, KT) do { _Pragma("unroll") for (int c_ = 0; c_ < 3; ++c_) \
    GLDS16(Bp + rB + (size_t)(c_ * 64) * K + (size_t)(KT) * 64, \
           sdB + (D) * 24576 + c_ * 8192); } while (0)

  const int sw = (qi & 7) << 4;
  const char* frA = smem + (wm * 64 + qi) * 128;
  const char* frB = smem + 65536 + (wn * 96 + qi) * 128;

#define QRDA(D, F0) do { _Pragma("unroll") for (int f_ = 0; f_ < 2; ++f_) \
    _Pragma("unroll") for (int k_ = 0; k_ < 2; ++k_) \
      a[(F0) + f_][k_] = *(const s8v*)(frA + (D) * 32768 + ((F0) + f_) * 2048 + (((k_ << 6) + (g << 4)) ^ sw)); } while (0)
#define QRDB(D, N0) do { _Pragma("unroll") for (int n_ = 0; n_ < 3; ++n_) \
    _Pragma("unroll") for (int k_ = 0; k_ < 2; ++k_) \
      b[(N0) + n_][k_] = *(const s8v*)(frB + (D) * 24576 + ((N0) + n_) * 2048 + (((k_ << 6) + (g << 4)) ^ sw)); } while (0)
#define QMQUAD(F0, N0) do { __builtin_amdgcn_s_setprio(1); \
    _Pragma("unroll") for (int f_ = 0; f_ < 2; ++f_) \
    _Pragma("unroll") for (int n_ = 0; n_ < 3; ++n_) \
    _Pragma("unroll") for (int k_ = 0; k_ < 2; ++k_) \
      mfma32(acc[(F0) + f_][(N0) + n_], a[(F0) + f_][k_], b[(N0) + n_][k_]); \
    __builtin_amdgcn_s_setprio(0); } while (0)

  f4v acc[4][6];
#pragma unroll
  for (int i = 0; i < 4; ++i)
#pragma unroll
    for (int j = 0; j < 6; ++j) acc[i][j] = (f4v)0.0f;

  QSTG_A(0, 0); QSTG_B(0, 0);
  QSTG_A(1, 1); QSTG_B(1, 1);
  WVM7;
  BAR;

  s8v a[4][2], b[6][2];
#pragma unroll 1
  for (int it = 0; it < NT / 2; ++it) {
    const int t = 2 * it;
    const int k2 = (t + 2 < NT) ? t + 2 : NT - 1;
    const int k3 = (t + 3 < NT) ? t + 3 : NT - 1;
    QRDA(0, 0); QRDB(0, 0);
    WLGKM; QMQUAD(0, 0); BAR;
    QRDB(0, 3);
    WLGKM; QMQUAD(0, 3); BAR;
    QRDA(0, 2);
    QSTG_B(0, k2);
    WLGKM; QMQUAD(2, 0); BAR;
    QSTG_A(0, k2);
    QMQUAD(2, 3);
    WVM7; BAR;
    QRDA(1, 0); QRDB(1, 0);
    WLGKM; QMQUAD(0, 0); BAR;
    QRDB(1, 3);
    WLGKM; QMQUAD(0, 3); BAR;
    QRDA(1, 2);
    QSTG_B(1, k3);
    WLGKM; QMQUAD(2, 0); BAR;
    QSTG_A(1, k3);
    QMQUAD(2, 3);
    WVM7; BAR;
  }

  asm volatile("s_waitcnt vmcnt(0)" ::: "memory");
  asm volatile("s_nop 7\n\ts_nop 7" ::: "memory");
  const int r4 = g * 4;
#pragma unroll
  for (int fm = 0; fm < 4; ++fm)
#pragma unroll
    for (int fn = 0; fn < 6; ++fn)
#pragma unroll
      for (int r = 0; r < 4; ++r)
        C[(size_t)(m0 + wm * 64 + fm * 16 + r4 + r) * N + (n0 + wn * 96 + fn * 16 + qi)] =
            f2b(acc[fm][fn][r]);
}

// ---------------------------------------------------------------------------
// 8-phase 256-sq GEMM (round-10 schedule v3, proven) — used for out-proj.
// ---------------------------------------------------------------------------
template <int OUTB>
__global__ __launch_bounds__(512, 2) void gemm_bt8(const unsigned short* __restrict__ A,
                                                   const unsigned short* __restrict__ Bp,
                                                   void* __restrict__ Cout,
                                                   int M, int N, int Ks, int Klen,
                                                   int nTiles) {
  __shared__ __align__(16) char smem[131072];
  const int tid = threadIdx.x, lane = tid & 63, wv = tid >> 6;
  const int qi = lane & 15, g = lane >> 4;
  const int wm = wv >> 2, wn = wv & 3;

  const int nwg = gridDim.x, cpx = nwg >> 3;
  const int id = blockIdx.x;
  const int swz = (id & 7) * cpx + (id >> 3);
  const int half = swz / nTiles;
  const int tile = swz - half * nTiles;
  const int kOff = half * Klen;
  const int MT = M >> 8;
  const int m0 = (tile % MT) * 256, n0 = (tile / MT) * 256;
  const int NT = Klen >> 6;

  const int srowo = wv * 8 + (lane >> 3);
  const int scole = ((lane & 7) ^ (lane >> 3)) << 3;
  const size_t rA = (size_t)(m0 + srowo) * Ks + kOff + scole;
  const size_t rB = (size_t)(n0 + srowo) * Ks + kOff + scole;
  char* sdA = smem + wv * 1024;
  char* sdB = smem + 32768 + wv * 1024;

#define STG_A(D, H, KT) do { \
    GLDS16(A + rA + (size_t)((H)*128) * Ks + (size_t)(KT)*64,      sdA + (D)*65536 + (H)*16384); \
    GLDS16(A + rA + (size_t)((H)*128 + 64) * Ks + (size_t)(KT)*64, sdA + (D)*65536 + (H)*16384 + 8192); } while (0)
#define STG_B(D, H, KT) do { \
    GLDS16(Bp + rB + (size_t)((H)*128) * Ks + (size_t)(KT)*64,      sdB + (D)*65536 + (H)*16384); \
    GLDS16(Bp + rB + (size_t)((H)*128 + 64) * Ks + (size_t)(KT)*64, sdB + (D)*65536 + (H)*16384 + 8192); } while (0)

  const int sw = (qi & 7) << 4;
  const char* frA = smem + (wm * 128 + qi) * 128;
  const char* frB = smem + 32768 + (wn * 64 + qi) * 128;

#define RDA4(D, F0) do { _Pragma("unroll") for (int f_ = 0; f_ < 4; ++f_) \
    _Pragma("unroll") for (int k_ = 0; k_ < 2; ++k_) \
      a[(F0) + f_][k_] = *(const s8v*)(frA + (D)*65536 + ((F0) + f_) * 2048 + (((k_ << 6) + (g << 4)) ^ sw)); } while (0)
#define RDB2(D, N0) do { _Pragma("unroll") for (int n_ = 0; n_ < 2; ++n_) \
    _Pragma("unroll") for (int k_ = 0; k_ < 2; ++k_) \
      b[(N0) + n_][k_] = *(const s8v*)(frB + (D)*65536 + ((N0) + n_) * 2048 + (((k_ << 6) + (g << 4)) ^ sw)); } while (0)
#define MQUAD(F0, N0) do { __builtin_amdgcn_s_setprio(1); \
    _Pragma("unroll") for (int f_ = 0; f_ < 4; ++f_) \
    _Pragma("unroll") for (int n_ = 0; n_ < 2; ++n_) \
    _Pragma("unroll") for (int k_ = 0; k_ < 2; ++k_) \
      mfma32(acc[(F0) + f_][(N0) + n_], a[(F0) + f_][k_], b[(N0) + n_][k_]); \
    __builtin_amdgcn_s_setprio(0); } while (0)

  f4v acc[8][4];
#pragma unroll
  for (int i = 0; i < 8; ++i)
#pragma unroll
    for (int j = 0; j < 4; ++j) acc[i][j] = (f4v)0.0f;

  STG_A(0, 0, 0); STG_A(0, 1, 0); STG_B(0, 0, 0); STG_B(0, 1, 0);
  STG_A(1, 0, 1); STG_A(1, 1, 1); STG_B(1, 0, 1); STG_B(1, 1, 1);
  WVM8;
  BAR;

  s8v a[8][2], b[4][2];
#pragma unroll 1
  for (int it = 0; it < NT / 2; ++it) {
    const int t = 2 * it;
    const int k2 = (t + 2 < NT) ? t + 2 : NT - 1;
    const int k3 = (t + 3 < NT) ? t + 3 : NT - 1;
    RDA4(0, 0); RDB2(0, 0);
    WLGKM; MQUAD(0, 0); BAR;
    RDB2(0, 2);
    WLGKM; MQUAD(0, 2); BAR;
    RDA4(0, 4);
    STG_B(0, 0, k2); STG_B(0, 1, k2);
    WLGKM; MQUAD(4, 0); BAR;
    STG_A(0, 0, k2); STG_A(0, 1, k2);
    MQUAD(4, 2);
    WVM8; BAR;
    RDA4(1, 0); RDB2(1, 0);
    WLGKM; MQUAD(0, 0); BAR;
    RDB2(1, 2);
    WLGKM; MQUAD(0, 2); BAR;
    RDA4(1, 4);
    STG_B(1, 0, k3); STG_B(1, 1, k3);
    WLGKM; MQUAD(4, 0); BAR;
    STG_A(1, 0, k3); STG_A(1, 1, k3);
    MQUAD(4, 2);
    WVM8; BAR;
  }

  asm volatile("s_waitcnt vmcnt(0)" ::: "memory");
  asm volatile("s_nop 7\n\ts_nop 7" ::: "memory");
  const int r4 = g * 4;
  if (OUTB) {
    unsigned short* Cb = (unsigned short*)Cout + (size_t)half * M * N;
#pragma unroll
    for (int fm = 0; fm < 8; ++fm)
#pragma unroll
      for (int fn = 0; fn < 4; ++fn)
#pragma unroll
        for (int r = 0; r < 4; ++r)
          Cb[(size_t)(m0 + wm * 128 + fm * 16 + r4 + r) * N + (n0 + wn * 64 + fn * 16 + qi)] =
              f2b(acc[fm][fn][r]);
  } else {
    float* Cf = (float*)Cout;
#pragma unroll
    for (int fm = 0; fm < 8; ++fm)
#pragma unroll
      for (int fn = 0; fn < 4; ++fn)
#pragma unroll
        for (int r = 0; r < 4; ++r)
          Cf[(size_t)(m0 + wm * 128 + fm * 16 + r4 + r) * N + (n0 + wn * 64 + fn * 16 + qi)] =
              acc[fm][fn][r];
  }
}

// ---------------------------------------------------------------------------
// RoPE + scatter (coalesced separate pass; single qkv buffer, Q pre-scaled)
// ---------------------------------------------------------------------------
__global__ __launch_bounds__(256) void rope_scatter(
    const unsigned short* __restrict__ qkvp, const float* __restrict__ fr,
    const float* __restrict__ fi,
    unsigned short* __restrict__ qb, unsigned short* __restrict__ kb,
    unsigned short* __restrict__ vbuf, float* __restrict__ xk, float* __restrict__ xv) {
  const int idx = blockIdx.x * 256 + threadIdx.x;
  const int token = idx / 3072;
  const int col2  = (idx - token * 3072) * 2;
  const int pos   = token & 2047;
  const unsigned u1 = *(const unsigned*)(qkvp + (size_t)token * 6144 + col2);
  float v0 = b2f((unsigned short)u1);
  float v1 = b2f((unsigned short)(u1 >> 16));
  if (col2 < 4096) {
    const int j = (col2 & 127) >> 1;
    const float cr = fr[pos * 64 + j], ci = fi[pos * 64 + j];
    const float a = (v0 * cr - ci * v1) * SCL_LOG2;
    const float o = (v0 * ci + v1 * cr) * SCL_LOG2;
    *(unsigned*)(qb + (size_t)token * 4096 + col2) = pk2(a, o);
  } else if (col2 < 5120) {
    const int lc = col2 - 4096;
    const int j = (lc & 127) >> 1;
    const float cr = fr[pos * 64 + j], ci = fi[pos * 64 + j];
    const float a = v0 * cr - ci * v1;
    const float o = v0 * ci + v1 * cr;
    *(unsigned*)(kb + (size_t)token * 1024 + lc) = pk2(a, o);
    f2v w; w.x = a; w.y = o;
    *(f2v*)(xk + (size_t)token * 1024 + lc) = w;
  } else {
    const int lc = col2 - 5120;
    *(unsigned*)(vbuf + (size_t)token * 1024 + lc) = u1;
    f2v w; w.x = v0; w.y = v1;
    *(f2v*)(xv + (size_t)token * 1024 + lc) = w;
  }
}

// ---------------------------------------------------------------------------
// Causal GQA flash attention — 4-wave blocks, 2 blocks/CU, single-barrier
// tile, V staged early (full-tile slack), in-place softmax.
// (LDS-port-bound floor for this decomposition: predicted MfmaUtil 15.4% ==
//  measured 15.5%.)
// ---------------------------------------------------------------------------
__global__ __launch_bounds__(256, 2) void attn_fwd(
    const unsigned short* __restrict__ qb, const unsigned short* __restrict__ kb,
    const unsigned short* __restrict__ vb, unsigned short* __restrict__ ao) {
  __shared__ __align__(16) char smem[81920];
  const int tid = threadIdx.x, lane = tid & 63, wv = tid >> 6;   // wv 0..3
  const int q31 = lane & 31, hi = lane >> 5;
  const int qtb = 15 - blockIdx.x;             // long blocks launch first
  const int h = blockIdx.y, b = blockIdx.z, kvh = h >> 2;
  const int q0 = qtb * 128;
  const int qrow = q0 + wv * 32 + q31;

  s8v qf[8];
  {
    const unsigned short* qp = qb + (size_t)(b * 2048 + qrow) * 4096 + h * 128 + hi * 8;
#pragma unroll
    for (int c = 0; c < 8; ++c) qf[c] = *(const s8v*)(qp + c * 16);
  }

  f16v oacc[4];
#pragma unroll
  for (int i = 0; i < 4; ++i) oacc[i] = (f16v)0.0f;
  float m_run = -3.0e38f, l_run = 0.0f;

  const unsigned short* ksrc[4]; int kdo[4];
#pragma unroll
  for (int j = 0; j < 4; ++j) {
    const int r = wv * 16 + j * 4 + (lane >> 4);
    ksrc[j] = kb + (size_t)(b * 2048 + r) * 1024 + kvh * 128 + (((lane & 15) ^ (r & 15)) << 3);
    kdo[j] = (wv * 16 + j * 4) * 256;
  }
  const unsigned short* vsrc[4]; int vdo[4];
#pragma unroll
  for (int j = 0; j < 4; ++j) {
    const int key = wv * 16 + j * 4 + ((lane & 7) >> 1);
    const int d = ((lane >> 3) & 7) * 16 + (lane & 1) * 8;
    vsrc[j] = vb + (size_t)(b * 2048 + key) * 1024 + kvh * 128 + d;
    vdo[j] = (wv * 32 + j * 8) * 128;
  }

  const int ntiles = 2 * qtb + 2;
  const int my_qmax = q0 + wv * 32 + 31, wq_lo = q0 + wv * 32;

  {
    char* k0d = smem;
    char* k1d = smem + 16384;
    char* v0d = smem + 49152;
#pragma unroll
    for (int j = 0; j < 4; ++j) GLDS16(ksrc[j], k0d + kdo[j]);
#pragma unroll
    for (int j = 0; j < 4; ++j) GLDS16(ksrc[j] + 65536, k1d + kdo[j]);
#pragma unroll
    for (int j = 0; j < 4; ++j) GLDS16(vsrc[j], v0d + vdo[j]);
  }
  asm volatile("s_waitcnt vmcnt(8)" ::: "memory");
  __builtin_amdgcn_sched_barrier(0);
  BAR;

  int kc = 0;
  for (int t = 0; t < ntiles; ++t) {
    const int k0 = t * 64;
    const bool live = (k0 <= my_qmax);
    const char* Kbase = smem + kc * 16384;
    f16v s32a = (f16v)0.0f, s32b = (f16v)0.0f;
    if (live) {
      __builtin_amdgcn_s_setprio(1);
#pragma unroll
      for (int c = 0; c < 8; ++c) {
        const int sl = ((2 * c + hi) ^ (q31 & 15)) << 4;
        s8v kfa = *(const s8v*)(Kbase + q31 * 256 + sl);
        s8v kfb = *(const s8v*)(Kbase + (32 + q31) * 256 + sl);
        mfma3216(s32a, kfa, qf[c]);
        mfma3216(s32b, kfb, qf[c]);
      }
      __builtin_amdgcn_s_setprio(0);
      asm volatile("s_nop 7\n\ts_nop 7\n\ts_nop 7" : "+v"(s32a), "+v"(s32b));
    }
    {                                          // stage K(t+2) -> slot (kc+2)%3
      const int kt2 = (t + 2 < ntiles) ? t + 2 : ntiles - 1;
      char* kd = smem + ((kc >= 1) ? kc - 1 : 2) * 16384;
#pragma unroll
      for (int j = 0; j < 4; ++j) GLDS16(ksrc[j] + (size_t)kt2 * 65536, kd + kdo[j]);
    }
    asm volatile("s_waitcnt vmcnt(4)" ::: "memory");  // drains K(t+1), V(t)
    __builtin_amdgcn_sched_barrier(0);
    BAR;                                       // single barrier per tile
    {                                          // stage V(t+1) EARLY: full-tile slack
      const int vt1 = (t + 1 < ntiles) ? t + 1 : ntiles - 1;
      char* vd = smem + 49152 + ((t + 1) & 1) * 16384;
#pragma unroll
      for (int j = 0; j < 4; ++j) GLDS16(vsrc[j] + (size_t)vt1 * 65536, vd + vdo[j]);
    }
    if (live) {
      const char* vbt = smem + 49152 + (t & 1) * 16384 + hi * 2048 +
                        ((lane >> 4) & 1) * 128 + ((lane & 15) << 3);
      s4v tA[8], tB[8];
#pragma unroll
      for (int u = 0; u < 8; ++u) tA[u] = tr_read(vbt, (u >> 1) * 256 + (u & 1) * 1024);

      // ---- softmax fully in place on s32a/s32b
      float tm = -3.0e38f;
      if (k0 + 64 <= wq_lo) {                  // fully unmasked (Q pre-scaled)
#pragma unroll
        for (int r = 0; r < 16; ++r) {
          tm = fmaxf(tm, s32a[r]);
          tm = fmaxf(tm, s32b[r]);
        }
      } else {                                 // diagonal/partial tile
#pragma unroll
        for (int r = 0; r < 16; ++r) {
          const int kga = k0 + (r & 3) + 8 * ((r >> 2) & 3) + 4 * hi;
          s32a[r] = (kga <= qrow) ? s32a[r] : -3.0e38f;
          tm = fmaxf(tm, s32a[r]);
          const int kgb = kga + 32;
          s32b[r] = (kgb <= qrow) ? s32b[r] : -3.0e38f;
          tm = fmaxf(tm, s32b[r]);
        }
      }
      tm = fmaxf(tm, __shfl_xor(tm, 32));

      if (!__all(tm - m_run <= 8.0f)) {        // T13 defer-max
        const float m_new = fmaxf(m_run, tm);
        const float al = exp2f(m_run - m_new);
#pragma unroll
        for (int i = 0; i < 4; ++i)
#pragma unroll
          for (int r = 0; r < 16; ++r) oacc[i][r] *= al;
        l_run *= al;
        m_run = m_new;
      }
      float ps = 0.0f;
#pragma unroll
      for (int r = 0; r < 16; ++r) {
        s32a[r] = exp2f(s32a[r] - m_run); ps += s32a[r];
        s32b[r] = exp2f(s32b[r] - m_run); ps += s32b[r];
      }
      ps += __shfl_xor(ps, 32);
      l_run += ps;

      // ---- P -> bf16 B-frags from s32a/s32b (literal-constant indices)
      s8v pf[4];
#define PFMAKE(KS, V, O) do { unsigned c0, c1, c2, c3; \
        asm("v_cvt_pk_bf16_f32 %0, %1, %2" : "=v"(c0) : "v"(V[(O)+0]), "v"(V[(O)+1])); \
        asm("v_cvt_pk_bf16_f32 %0, %1, %2" : "=v"(c1) : "v"(V[(O)+2]), "v"(V[(O)+3])); \
        asm("v_cvt_pk_bf16_f32 %0, %1, %2" : "=v"(c2) : "v"(V[(O)+4]), "v"(V[(O)+5])); \
        asm("v_cvt_pk_bf16_f32 %0, %1, %2" : "=v"(c3) : "v"(V[(O)+6]), "v"(V[(O)+7])); \
        asm volatile("v_permlane32_swap_b32 %0, %1" : "+v"(c0), "+v"(c2)); \
        asm volatile("v_permlane32_swap_b32 %0, %1" : "+v"(c1), "+v"(c3)); \
        u4v pw; pw.x = c0; pw.y = c1; pw.z = c2; pw.w = c3; \
        pf[KS] = __builtin_bit_cast(s8v, pw); } while (0)
      PFMAKE(0, s32a, 0);
      PFMAKE(1, s32a, 8);
      PFMAKE(2, s32b, 0);
      PFMAKE(3, s32b, 8);
#undef PFMAKE

#define PVS(KS, CUR, NXT, LAST) do { \
        if (!(LAST)) { \
          _Pragma("unroll") for (int u = 0; u < 8; ++u) \
            NXT[u] = tr_read(vbt, ((KS)+1)*4096 + (u >> 1) * 256 + (u & 1) * 1024); \
          asm volatile("s_waitcnt lgkmcnt(8)" ::: "memory"); \
        } else { asm volatile("s_waitcnt lgkmcnt(0)" ::: "memory"); } \
        __builtin_amdgcn_sched_barrier(0); \
        __builtin_amdgcn_s_setprio(1); \
        _Pragma("unroll") for (int dt = 0; dt < 4; ++dt) { \
          s8v vf = __builtin_shufflevector(CUR[dt*2], CUR[dt*2+1], 0,1,2,3,4,5,6,7); \
          mfma3216(oacc[dt], vf, pf[KS]); } \
        __builtin_amdgcn_s_setprio(0); \
      } while (0)
      PVS(0, tA, tB, 0);
      PVS(1, tB, tA, 0);
      PVS(2, tA, tB, 0);
      PVS(3, tB, tA, 1);
#undef PVS
    }
    kc = (kc == 2) ? 0 : kc + 1;
  }

  // ---- epilogue: O -> swizzled f32 LDS (2 passes of 2 waves) -> bf16 stores
  asm volatile("s_waitcnt vmcnt(0) lgkmcnt(0)" ::: "memory");
  asm volatile("s_nop 7\n\ts_nop 7\n\ts_nop 7" ::: "memory");
  __syncthreads();
  const float inv = 1.0f / l_run;
  float* Ost = (float*)smem;
  const int er = tid >> 2, ew = (tid & 3) * 32;
#pragma unroll
  for (int p = 0; p < 2; ++p) {
    if ((wv >> 1) == p) {
      const int qip = (wv & 1) * 32 + q31;
#pragma unroll
      for (int dt = 0; dt < 4; ++dt)
#pragma unroll
        for (int r = 0; r < 16; ++r) {
          const int d = dt * 32 + (r & 3) + 8 * ((r >> 2) & 3) + 4 * hi;
          Ost[qip * 128 + (d ^ ((qip & 7) << 2))] = oacc[dt][r] * inv;
        }
    }
    __syncthreads();
    const int sw = (er & 7) << 2;
    f4v av[8];
#pragma unroll
    for (int c = 0; c < 8; ++c)
      av[c] = *(const f4v*)(Ost + er * 128 + ((ew + c * 4) ^ sw));
    u4v r0, r1;
    r0.x = pk2(av[0][0], av[0][1]); r0.y = pk2(av[0][2], av[0][3]);
    r0.z = pk2(av[1][0], av[1][1]); r0.w = pk2(av[1][2], av[1][3]);
    r1.x = pk2(av[2][0], av[2][1]); r1.y = pk2(av[2][2], av[2][3]);
    r1.z = pk2(av[3][0], av[3][1]); r1.w = pk2(av[3][2], av[3][3]);
    u4v r2, r3;
    r2.x = pk2(av[4][0], av[4][1]); r2.y = pk2(av[4][2], av[4][3]);
    r2.z = pk2(av[5][0], av[5][1]); r2.w = pk2(av[5][2], av[5][3]);
    r3.x = pk2(av[6][0], av[6][1]); r3.y = pk2(av[6][2], av[6][3]);
    r3.z = pk2(av[7][0], av[7][1]); r3.w = pk2(av[7][2], av[7][3]);
    unsigned short* dst = ao + (size_t)(b * 2048 + q0 + p * 64 + er) * 4096 + h * 128 + ew;
    *(u4v*)dst = r0;
    *(u4v*)(dst + 8) = r1;
    *(u4v*)(dst + 16) = r2;
    *(u4v*)(dst + 24) = r3;
    __syncthreads();
  }
}

// ---------------------------------------------------------------------------
// Host launcher. Workspace (needs ws_size >= 268,435,456 B):
//   [0,32M)     xb bf16        [32M,80M)   wqkv bf16
//   [80M,112M)  wo bf16        [112M,160M) qkv bf16 single [4096][6144]
//   [160M,193.5M) attn_out bf16 (aob)
//   [208M,240M) q bf16         [240M,248M) k bf16    [248M,256M) v bf16
// ---------------------------------------------------------------------------
extern "C" void kernel_launch(void* const* d_in, const int* in_sizes, int n_in,
                              void* d_out, int out_size, void* d_ws, size_t ws_size,
                              hipStream_t stream) {
  (void)in_sizes; (void)n_in; (void)out_size; (void)ws_size;
  const float* x  = (const float*)d_in[0];
  const float* wq = (const float*)d_in[1];
  const float* wk = (const float*)d_in[2];
  const float* wv = (const float*)d_in[3];
  const float* wo = (const float*)d_in[4];
  const float* fr = (const float*)d_in[5];
  const float* fi = (const float*)d_in[6];

  float* out = (float*)d_out;
  float* xk  = out + 16777216;
  float* xv  = xk + 4194304;

  char* ws = (char*)d_ws;
  unsigned short* xb    = (unsigned short*)(ws);
  unsigned short* wqkvb = (unsigned short*)(ws + 33554432);
  unsigned short* wob   = (unsigned short*)(ws + 83886080);
  unsigned short* qkvb  = (unsigned short*)(ws + 117440512);  // 48MB bf16
  unsigned short* aob   = (unsigned short*)(ws + 167772160);  // 33.5MB bf16
  unsigned short* qbuf  = (unsigned short*)(ws + 218103808);
  unsigned short* kbuf  = (unsigned short*)(ws + 251658240);
  unsigned short* vbuf  = (unsigned short*)(ws + 260046848);

  // single merged convert launch (was 5)
  cvt_all<<<57344, 256, 0, stream>>>(x, wq, wk, wv, wo, xb, wqkvb, wob);

  // qkv: 256x192 tiles, full K -> 512 blocks = 2 exact rounds on 256 CUs
  gemm_qkv<<<512, 512, 0, stream>>>(xb, wqkvb, qkvb);
  rope_scatter<<<49152, 256, 0, stream>>>(qkvb, fr, fi, qbuf, kbuf, vbuf, xk, xv);
  attn_fwd<<<dim3(16, 32, 2), 256, 0, stream>>>(qbuf, kbuf, vbuf, aob);
  gemm_bt8<0><<<256, 512, 0, stream>>>(aob, wob, out, 4096, 4096, 4096, 4096, 256);
}

// Round 21
// 545.710 us; speedup vs baseline: 1.0394x; 1.0026x over previous
//
#include <hip/hip_runtime.h>
#include <hip/hip_bf16.h>

// ---------------------------------------------------------------------------
// Attention block: B=2 S=2048 D=4096 H=32 KV=8 HD=128 (GQA N_REP=4, causal)
// Pipeline: cvt_all(1) -> GEMM-qkv(256x192) -> RoPE-KV/scatter
//           -> flash-attn(4-wave, Q-RoPE fused at load) -> GEMM8-256sq(out)
// Round 21: Q-RoPE moved into attention's Q-load (each Q element read exactly
// once there -> zero redundancy); rope pass is K/V-only (-64 MB traffic).
// ---------------------------------------------------------------------------

typedef __attribute__((ext_vector_type(8)))  short s8v;   // 8 x bf16 (4 VGPR)
typedef __attribute__((ext_vector_type(4)))  short s4v;   // 4 x bf16 (2 VGPR)
typedef __attribute__((ext_vector_type(4)))  float f4v;
typedef __attribute__((ext_vector_type(16))) float f16v;  // 32x32 MFMA acc
typedef __attribute__((ext_vector_type(2)))  float f2v;
typedef __attribute__((ext_vector_type(2))) unsigned int u2v;
typedef __attribute__((ext_vector_type(4))) unsigned int u4v;

typedef __attribute__((address_space(3))) void lds_void;
typedef __attribute__((address_space(1))) void g_void;

#define GLDS16(gp, lp) __builtin_amdgcn_global_load_lds((g_void*)(gp), (lds_void*)(lp), 16, 0, 0)

#define SCL_LOG2 0.12751744f   // (1/sqrt(128)) * log2(e); folded into Q rotate

__device__ __forceinline__ unsigned short f2b(float f) {  // f32 -> bf16 RNE
  unsigned u = __builtin_bit_cast(unsigned, f);
  u += 0x7fffu + ((u >> 16) & 1u);
  return (unsigned short)(u >> 16);
}
__device__ __forceinline__ unsigned pk2(float a, float b) {
  return (unsigned)f2b(a) | ((unsigned)f2b(b) << 16);
}
__device__ __forceinline__ float b2f(unsigned short h) {
  return __builtin_bit_cast(float, (unsigned)h << 16);
}

// inline-asm MFMAs (volatile; s_nop guards at every MFMA->VALU read-back)
__device__ __forceinline__ void mfma32(f4v& d, s8v a, s8v b) {
  asm volatile("v_mfma_f32_16x16x32_bf16 %0, %1, %2, %0" : "+v"(d) : "v"(a), "v"(b));
}
__device__ __forceinline__ void mfma3216(f16v& d, s8v a, s8v b) {
  asm volatile("v_mfma_f32_32x32x16_bf16 %0, %1, %2, %0" : "+v"(d) : "v"(a), "v"(b));
}
__device__ __forceinline__ s4v tr_read(const char* p, int imm) {
  s4v r;
  asm volatile("ds_read_b64_tr_b16 %0, %1 offset:%2"
               : "=v"(r) : "v"((lds_void*)p), "n"(imm));
  return r;
}

// ---------------------------------------------------------------------------
// Merged f32 -> bf16 convert: one launch covers x|wq|wk|wv|wo.
// ---------------------------------------------------------------------------
__global__ __launch_bounds__(256) void cvt_all(
    const float* __restrict__ x,  const float* __restrict__ wq,
    const float* __restrict__ wk, const float* __restrict__ wv,
    const float* __restrict__ wo,
    unsigned short* __restrict__ xb, unsigned short* __restrict__ wqkvb,
    unsigned short* __restrict__ wob) {
  const int i = blockIdx.x * 256 + threadIdx.x;
  const float* s;
  unsigned short* d;
  int o;
  if (i < 4194304)        { s = x;  d = xb;               o = i; }
  else if (i < 8388608)   { s = wq; d = wqkvb;            o = i - 4194304; }
  else if (i < 9437184)   { s = wk; d = wqkvb + 16777216; o = i - 8388608; }
  else if (i < 10485760)  { s = wv; d = wqkvb + 20971520; o = i - 9437184; }
  else                    { s = wo; d = wob;              o = i - 10485760; }
  f4v v = *(const f4v*)(s + (size_t)o * 4);
  u2v r;
  r.x = pk2(v[0], v[1]);
  r.y = pk2(v[2], v[3]);
  *(u2v*)(d + (size_t)o * 4) = r;
}

// ---------------------------------------------------------------------------
// sync macros shared by GEMM kernels
// ---------------------------------------------------------------------------
#define BAR      asm volatile("s_barrier" ::: "memory")
#define WLGKM    do { asm volatile("s_waitcnt lgkmcnt(0)" ::: "memory"); \
                      __builtin_amdgcn_sched_barrier(0); } while (0)
#define WVM8     do { asm volatile("s_waitcnt vmcnt(8)" ::: "memory"); \
                      __builtin_amdgcn_sched_barrier(0); } while (0)
#define WVM7     do { asm volatile("s_waitcnt vmcnt(7)" ::: "memory"); \
                      __builtin_amdgcn_sched_barrier(0); } while (0)

// ---------------------------------------------------------------------------
// qkv GEMM: 256x192 tile, full K=4096, 512 blocks = 2 exact rounds.
// ---------------------------------------------------------------------------
__global__ __launch_bounds__(512, 2) void gemm_qkv(const unsigned short* __restrict__ A,
                                                   const unsigned short* __restrict__ Bp,
                                                   unsigned short* __restrict__ C) {
  __shared__ __align__(16) char smem[114688];
  const int tid = threadIdx.x, lane = tid & 63, wv = tid >> 6;
  const int qi = lane & 15, g = lane >> 4;
  const int wm = wv >> 1, wn = wv & 1;          // 4M x 2N
  const int K = 4096, N = 6144, NT = 64;

  const int id = blockIdx.x;
  const int swz = (id & 7) * 64 + (id >> 3);
  const int m0 = (swz & 15) * 256, n0 = (swz >> 4) * 192;

  const int srowo = wv * 8 + (lane >> 3);
  const int scole = ((lane & 7) ^ (lane >> 3)) << 3;
  const size_t rA = (size_t)(m0 + srowo) * K + scole;
  const size_t rB = (size_t)(n0 + srowo) * K + scole;
  char* sdA = smem + wv * 1024;
  char* sdB = smem + 65536 + wv * 1024;

#define QSTG_A(D, KT) do { _Pragma("unroll") for (int c_ = 0; c_ < 4; ++c_) \
    GLDS16(A + rA + (size_t)(c_ * 64) * K + (size_t)(KT) * 64, \
           sdA + (D) * 32768 + c_ * 8192); } while (0)
#define QSTG_B(D, KT) do { _Pragma("unroll") for (int c_ = 0; c_ < 3; ++c_) \
    GLDS16(Bp + rB + (size_t)(c_ * 64) * K + (size_t)(KT) * 64, \
           sdB + (D) * 24576 + c_ * 8192); } while (0)

  const int sw = (qi & 7) << 4;
  const char* frA = smem + (wm * 64 + qi) * 128;
  const char* frB = smem + 65536 + (wn * 96 + qi) * 128;

#define QRDA(D, F0) do { _Pragma("unroll") for (int f_ = 0; f_ < 2; ++f_) \
    _Pragma("unroll") for (int k_ = 0; k_ < 2; ++k_) \
      a[(F0) + f_][k_] = *(const s8v*)(frA + (D) * 32768 + ((F0) + f_) * 2048 + (((k_ << 6) + (g << 4)) ^ sw)); } while (0)
#define QRDB(D, N0) do { _Pragma("unroll") for (int n_ = 0; n_ < 3; ++n_) \
    _Pragma("unroll") for (int k_ = 0; k_ < 2; ++k_) \
      b[(N0) + n_][k_] = *(const s8v*)(frB + (D) * 24576 + ((N0) + n_) * 2048 + (((k_ << 6) + (g << 4)) ^ sw)); } while (0)
#define QMQUAD(F0, N0) do { __builtin_amdgcn_s_setprio(1); \
    _Pragma("unroll") for (int f_ = 0; f_ < 2; ++f_) \
    _Pragma("unroll") for (int n_ = 0; n_ < 3; ++n_) \
    _Pragma("unroll") for (int k_ = 0; k_ < 2; ++k_) \
      mfma32(acc[(F0) + f_][(N0) + n_], a[(F0) + f_][k_], b[(N0) + n_][k_]); \
    __builtin_amdgcn_s_setprio(0); } while (0)

  f4v acc[4][6];
#pragma unroll
  for (int i = 0; i < 4; ++i)
#pragma unroll
    for (int j = 0; j < 6; ++j) acc[i][j] = (f4v)0.0f;

  QSTG_A(0, 0); QSTG_B(0, 0);
  QSTG_A(1, 1); QSTG_B(1, 1);
  WVM7;
  BAR;

  s8v a[4][2], b[6][2];
#pragma unroll 1
  for (int it = 0; it < NT / 2; ++it) {
    const int t = 2 * it;
    const int k2 = (t + 2 < NT) ? t + 2 : NT - 1;
    const int k3 = (t + 3 < NT) ? t + 3 : NT - 1;
    QRDA(0, 0); QRDB(0, 0);
    WLGKM; QMQUAD(0, 0); BAR;
    QRDB(0, 3);
    WLGKM; QMQUAD(0, 3); BAR;
    QRDA(0, 2);
    QSTG_B(0, k2);
    WLGKM; QMQUAD(2, 0); BAR;
    QSTG_A(0, k2);
    QMQUAD(2, 3);
    WVM7; BAR;
    QRDA(1, 0); QRDB(1, 0);
    WLGKM; QMQUAD(0, 0); BAR;
    QRDB(1, 3);
    WLGKM; QMQUAD(0, 3); BAR;
    QRDA(1, 2);
    QSTG_B(1, k3);
    WLGKM; QMQUAD(2, 0); BAR;
    QSTG_A(1, k3);
    QMQUAD(2, 3);
    WVM7; BAR;
  }

  asm volatile("s_waitcnt vmcnt(0)" ::: "memory");
  asm volatile("s_nop 7\n\ts_nop 7" ::: "memory");
  const int r4 = g * 4;
#pragma unroll
  for (int fm = 0; fm < 4; ++fm)
#pragma unroll
    for (int fn = 0; fn < 6; ++fn)
#pragma unroll
      for (int r = 0; r < 4; ++r)
        C[(size_t)(m0 + wm * 64 + fm * 16 + r4 + r) * N + (n0 + wn * 96 + fn * 16 + qi)] =
            f2b(acc[fm][fn][r]);
}

// ---------------------------------------------------------------------------
// 8-phase 256-sq GEMM (round-10 schedule v3, proven) — used for out-proj.
// ---------------------------------------------------------------------------
template <int OUTB>
__global__ __launch_bounds__(512, 2) void gemm_bt8(const unsigned short* __restrict__ A,
                                                   const unsigned short* __restrict__ Bp,
                                                   void* __restrict__ Cout,
                                                   int M, int N, int Ks, int Klen,
                                                   int nTiles) {
  __shared__ __align__(16) char smem[131072];
  const int tid = threadIdx.x, lane = tid & 63, wv = tid >> 6;
  const int qi = lane & 15, g = lane >> 4;
  const int wm = wv >> 2, wn = wv & 3;

  const int nwg = gridDim.x, cpx = nwg >> 3;
  const int id = blockIdx.x;
  const int swz = (id & 7) * cpx + (id >> 3);
  const int half = swz / nTiles;
  const int tile = swz - half * nTiles;
  const int kOff = half * Klen;
  const int MT = M >> 8;
  const int m0 = (tile % MT) * 256, n0 = (tile / MT) * 256;
  const int NT = Klen >> 6;

  const int srowo = wv * 8 + (lane >> 3);
  const int scole = ((lane & 7) ^ (lane >> 3)) << 3;
  const size_t rA = (size_t)(m0 + srowo) * Ks + kOff + scole;
  const size_t rB = (size_t)(n0 + srowo) * Ks + kOff + scole;
  char* sdA = smem + wv * 1024;
  char* sdB = smem + 32768 + wv * 1024;

#define STG_A(D, H, KT) do { \
    GLDS16(A + rA + (size_t)((H)*128) * Ks + (size_t)(KT)*64,      sdA + (D)*65536 + (H)*16384); \
    GLDS16(A + rA + (size_t)((H)*128 + 64) * Ks + (size_t)(KT)*64, sdA + (D)*65536 + (H)*16384 + 8192); } while (0)
#define STG_B(D, H, KT) do { \
    GLDS16(Bp + rB + (size_t)((H)*128) * Ks + (size_t)(KT)*64,      sdB + (D)*65536 + (H)*16384); \
    GLDS16(Bp + rB + (size_t)((H)*128 + 64) * Ks + (size_t)(KT)*64, sdB + (D)*65536 + (H)*16384 + 8192); } while (0)

  const int sw = (qi & 7) << 4;
  const char* frA = smem + (wm * 128 + qi) * 128;
  const char* frB = smem + 32768 + (wn * 64 + qi) * 128;

#define RDA4(D, F0) do { _Pragma("unroll") for (int f_ = 0; f_ < 4; ++f_) \
    _Pragma("unroll") for (int k_ = 0; k_ < 2; ++k_) \
      a[(F0) + f_][k_] = *(const s8v*)(frA + (D)*65536 + ((F0) + f_) * 2048 + (((k_ << 6) + (g << 4)) ^ sw)); } while (0)
#define RDB2(D, N0) do { _Pragma("unroll") for (int n_ = 0; n_ < 2; ++n_) \
    _Pragma("unroll") for (int k_ = 0; k_ < 2; ++k_) \
      b[(N0) + n_][k_] = *(const s8v*)(frB + (D)*65536 + ((N0) + n_) * 2048 + (((k_ << 6) + (g << 4)) ^ sw)); } while (0)
#define MQUAD(F0, N0) do { __builtin_amdgcn_s_setprio(1); \
    _Pragma("unroll") for (int f_ = 0; f_ < 4; ++f_) \
    _Pragma("unroll") for (int n_ = 0; n_ < 2; ++n_) \
    _Pragma("unroll") for (int k_ = 0; k_ < 2; ++k_) \
      mfma32(acc[(F0) + f_][(N0) + n_], a[(F0) + f_][k_], b[(N0) + n_][k_]); \
    __builtin_amdgcn_s_setprio(0); } while (0)

  f4v acc[8][4];
#pragma unroll
  for (int i = 0; i < 8; ++i)
#pragma unroll
    for (int j = 0; j < 4; ++j) acc[i][j] = (f4v)0.0f;

  STG_A(0, 0, 0); STG_A(0, 1, 0); STG_B(0, 0, 0); STG_B(0, 1, 0);
  STG_A(1, 0, 1); STG_A(1, 1, 1); STG_B(1, 0, 1); STG_B(1, 1, 1);
  WVM8;
  BAR;

  s8v a[8][2], b[4][2];
#pragma unroll 1
  for (int it = 0; it < NT / 2; ++it) {
    const int t = 2 * it;
    const int k2 = (t + 2 < NT) ? t + 2 : NT - 1;
    const int k3 = (t + 3 < NT) ? t + 3 : NT - 1;
    RDA4(0, 0); RDB2(0, 0);
    WLGKM; MQUAD(0, 0); BAR;
    RDB2(0, 2);
    WLGKM; MQUAD(0, 2); BAR;
    RDA4(0, 4);
    STG_B(0, 0, k2); STG_B(0, 1, k2);
    WLGKM; MQUAD(4, 0); BAR;
    STG_A(0, 0, k2); STG_A(0, 1, k2);
    MQUAD(4, 2);
    WVM8; BAR;
    RDA4(1, 0); RDB2(1, 0);
    WLGKM; MQUAD(0, 0); BAR;
    RDB2(1, 2);
    WLGKM; MQUAD(0, 2); BAR;
    RDA4(1, 4);
    STG_B(1, 0, k3); STG_B(1, 1, k3);
    WLGKM; MQUAD(4, 0); BAR;
    STG_A(1, 0, k3); STG_A(1, 1, k3);
    MQUAD(4, 2);
    WVM8; BAR;
  }

  asm volatile("s_waitcnt vmcnt(0)" ::: "memory");
  asm volatile("s_nop 7\n\ts_nop 7" ::: "memory");
  const int r4 = g * 4;
  if (OUTB) {
    unsigned short* Cb = (unsigned short*)Cout + (size_t)half * M * N;
#pragma unroll
    for (int fm = 0; fm < 8; ++fm)
#pragma unroll
      for (int fn = 0; fn < 4; ++fn)
#pragma unroll
        for (int r = 0; r < 4; ++r)
          Cb[(size_t)(m0 + wm * 128 + fm * 16 + r4 + r) * N + (n0 + wn * 64 + fn * 16 + qi)] =
              f2b(acc[fm][fn][r]);
  } else {
    float* Cf = (float*)Cout;
#pragma unroll
    for (int fm = 0; fm < 8; ++fm)
#pragma unroll
      for (int fn = 0; fn < 4; ++fn)
#pragma unroll
        for (int r = 0; r < 4; ++r)
          Cf[(size_t)(m0 + wm * 128 + fm * 16 + r4 + r) * N + (n0 + wn * 64 + fn * 16 + qi)] =
              acc[fm][fn][r];
  }
}

// ---------------------------------------------------------------------------
// RoPE K/V-only + scatter (Q handled inside attention). 4096 tokens x 1024
// element-pairs (cols 4096..6143 of qkv). Grid 16384 x 256 exact.
// ---------------------------------------------------------------------------
__global__ __launch_bounds__(256) void rope_kv(
    const unsigned short* __restrict__ qkvp, const float* __restrict__ fr,
    const float* __restrict__ fi,
    unsigned short* __restrict__ kb, unsigned short* __restrict__ vbuf,
    float* __restrict__ xk, float* __restrict__ xv) {
  const int idx = blockIdx.x * 256 + threadIdx.x;   // 4,194,304 total
  const int token = idx >> 10;
  const int lc2 = (idx & 1023) * 2;                 // local col pair in [0,2048)
  const int pos = token & 2047;
  const unsigned u1 = *(const unsigned*)(qkvp + (size_t)token * 6144 + 4096 + lc2);
  const float v0 = b2f((unsigned short)u1);
  const float v1 = b2f((unsigned short)(u1 >> 16));
  if (lc2 < 1024) {                                 // K: rope + bf16 + f32 out
    const int j = (lc2 & 127) >> 1;
    const float cr = fr[pos * 64 + j], ci = fi[pos * 64 + j];
    const float a = v0 * cr - ci * v1;
    const float o = v0 * ci + v1 * cr;
    *(unsigned*)(kb + (size_t)token * 1024 + lc2) = pk2(a, o);
    f2v w; w.x = a; w.y = o;
    *(f2v*)(xk + (size_t)token * 1024 + lc2) = w;
  } else {                                          // V: copy + f32 out
    const int lc = lc2 - 1024;
    *(unsigned*)(vbuf + (size_t)token * 1024 + lc) = u1;
    f2v w; w.x = v0; w.y = v1;
    *(f2v*)(xv + (size_t)token * 1024 + lc) = w;
  }
}

// ---------------------------------------------------------------------------
// Causal GQA flash attention — 4-wave blocks, 2 blocks/CU, single-barrier
// tile, V staged early, in-place softmax. Round-21: Q read DIRECTLY from the
// qkv GEMM output (stride 6144) with RoPE applied in-lane at load (each Q
// element is read exactly once across the dispatch -> zero redundancy).
// qf[c] holds 8 consecutive cols = 4 complete even/odd pairs; j = c*8+hi*4+u,
// pos = qrow; SCL_LOG2 folded in after rotation.
// ---------------------------------------------------------------------------
__global__ __launch_bounds__(256, 2) void attn_fwd(
    const unsigned short* __restrict__ qkvp, const unsigned short* __restrict__ kb,
    const unsigned short* __restrict__ vb, const float* __restrict__ fr,
    const float* __restrict__ fi, unsigned short* __restrict__ ao) {
  __shared__ __align__(16) char smem[81920];
  const int tid = threadIdx.x, lane = tid & 63, wv = tid >> 6;   // wv 0..3
  const int q31 = lane & 31, hi = lane >> 5;
  const int qtb = 15 - blockIdx.x;             // long blocks launch first
  const int h = blockIdx.y, b = blockIdx.z, kvh = h >> 2;
  const int q0 = qtb * 128;
  const int qrow = q0 + wv * 32 + q31;

  // ---- Q load from qkv GEMM output + in-lane RoPE (+ SCL_LOG2) ----
  s8v qf[8];
  {
    const unsigned short* qp = qkvp + (size_t)(b * 2048 + qrow) * 6144 + h * 128 + hi * 8;
    const float* frp = fr + (size_t)qrow * 64;
    const float* fip = fi + (size_t)qrow * 64;
#pragma unroll
    for (int c = 0; c < 8; ++c) {
      const s8v raw = *(const s8v*)(qp + c * 16);
      u4v pw;
#pragma unroll
      for (int u = 0; u < 4; ++u) {
        const float e = b2f((unsigned short)raw[2 * u]);
        const float o = b2f((unsigned short)raw[2 * u + 1]);
        const int j = c * 8 + hi * 4 + u;
        const float cr = frp[j], ci = fip[j];
        ((unsigned*)&pw)[u] = pk2((e * cr - ci * o) * SCL_LOG2,
                                  (e * ci + o * cr) * SCL_LOG2);
      }
      qf[c] = __builtin_bit_cast(s8v, pw);
    }
  }

  f16v oacc[4];
#pragma unroll
  for (int i = 0; i < 4; ++i) oacc[i] = (f16v)0.0f;
  float m_run = -3.0e38f, l_run = 0.0f;

  const unsigned short* ksrc[4]; int kdo[4];
#pragma unroll
  for (int j = 0; j < 4; ++j) {
    const int r = wv * 16 + j * 4 + (lane >> 4);
    ksrc[j] = kb + (size_t)(b * 2048 + r) * 1024 + kvh * 128 + (((lane & 15) ^ (r & 15)) << 3);
    kdo[j] = (wv * 16 + j * 4) * 256;
  }
  const unsigned short* vsrc[4]; int vdo[4];
#pragma unroll
  for (int j = 0; j < 4; ++j) {
    const int key = wv * 16 + j * 4 + ((lane & 7) >> 1);
    const int d = ((lane >> 3) & 7) * 16 + (lane & 1) * 8;
    vsrc[j] = vb + (size_t)(b * 2048 + key) * 1024 + kvh * 128 + d;
    vdo[j] = (wv * 32 + j * 8) * 128;
  }

  const int ntiles = 2 * qtb + 2;
  const int my_qmax = q0 + wv * 32 + 31, wq_lo = q0 + wv * 32;

  {
    char* k0d = smem;
    char* k1d = smem + 16384;
    char* v0d = smem + 49152;
#pragma unroll
    for (int j = 0; j < 4; ++j) GLDS16(ksrc[j], k0d + kdo[j]);
#pragma unroll
    for (int j = 0; j < 4; ++j) GLDS16(ksrc[j] + 65536, k1d + kdo[j]);
#pragma unroll
    for (int j = 0; j < 4; ++j) GLDS16(vsrc[j], v0d + vdo[j]);
  }
  asm volatile("s_waitcnt vmcnt(8)" ::: "memory");
  __builtin_amdgcn_sched_barrier(0);
  BAR;

  int kc = 0;
  for (int t = 0; t < ntiles; ++t) {
    const int k0 = t * 64;
    const bool live = (k0 <= my_qmax);
    const char* Kbase = smem + kc * 16384;
    f16v s32a = (f16v)0.0f, s32b = (f16v)0.0f;
    if (live) {
      __builtin_amdgcn_s_setprio(1);
#pragma unroll
      for (int c = 0; c < 8; ++c) {
        const int sl = ((2 * c + hi) ^ (q31 & 15)) << 4;
        s8v kfa = *(const s8v*)(Kbase + q31 * 256 + sl);
        s8v kfb = *(const s8v*)(Kbase + (32 + q31) * 256 + sl);
        mfma3216(s32a, kfa, qf[c]);
        mfma3216(s32b, kfb, qf[c]);
      }
      __builtin_amdgcn_s_setprio(0);
      asm volatile("s_nop 7\n\ts_nop 7\n\ts_nop 7" : "+v"(s32a), "+v"(s32b));
    }
    {                                          // stage K(t+2) -> slot (kc+2)%3
      const int kt2 = (t + 2 < ntiles) ? t + 2 : ntiles - 1;
      char* kd = smem + ((kc >= 1) ? kc - 1 : 2) * 16384;
#pragma unroll
      for (int j = 0; j < 4; ++j) GLDS16(ksrc[j] + (size_t)kt2 * 65536, kd + kdo[j]);
    }
    asm volatile("s_waitcnt vmcnt(4)" ::: "memory");  // drains K(t+1), V(t)
    __builtin_amdgcn_sched_barrier(0);
    BAR;                                       // single barrier per tile
    {                                          // stage V(t+1) EARLY: full-tile slack
      const int vt1 = (t + 1 < ntiles) ? t + 1 : ntiles - 1;
      char* vd = smem + 49152 + ((t + 1) & 1) * 16384;
#pragma unroll
      for (int j = 0; j < 4; ++j) GLDS16(vsrc[j] + (size_t)vt1 * 65536, vd + vdo[j]);
    }
    if (live) {
      const char* vbt = smem + 49152 + (t & 1) * 16384 + hi * 2048 +
                        ((lane >> 4) & 1) * 128 + ((lane & 15) << 3);
      s4v tA[8], tB[8];
#pragma unroll
      for (int u = 0; u < 8; ++u) tA[u] = tr_read(vbt, (u >> 1) * 256 + (u & 1) * 1024);

      // ---- softmax fully in place on s32a/s32b
      float tm = -3.0e38f;
      if (k0 + 64 <= wq_lo) {                  // fully unmasked (Q pre-scaled)
#pragma unroll
        for (int r = 0; r < 16; ++r) {
          tm = fmaxf(tm, s32a[r]);
          tm = fmaxf(tm, s32b[r]);
        }
      } else {                                 // diagonal/partial tile
#pragma unroll
        for (int r = 0; r < 16; ++r) {
          const int kga = k0 + (r & 3) + 8 * ((r >> 2) & 3) + 4 * hi;
          s32a[r] = (kga <= qrow) ? s32a[r] : -3.0e38f;
          tm = fmaxf(tm, s32a[r]);
          const int kgb = kga + 32;
          s32b[r] = (kgb <= qrow) ? s32b[r] : -3.0e38f;
          tm = fmaxf(tm, s32b[r]);
        }
      }
      tm = fmaxf(tm, __shfl_xor(tm, 32));

      if (!__all(tm - m_run <= 8.0f)) {        // T13 defer-max
        const float m_new = fmaxf(m_run, tm);
        const float al = exp2f(m_run - m_new);
#pragma unroll
        for (int i = 0; i < 4; ++i)
#pragma unroll
          for (int r = 0; r < 16; ++r) oacc[i][r] *= al;
        l_run *= al;
        m_run = m_new;
      }
      float ps = 0.0f;
#pragma unroll
      for (int r = 0; r < 16; ++r) {
        s32a[r] = exp2f(s32a[r] - m_run); ps += s32a[r];
        s32b[r] = exp2f(s32b[r] - m_run); ps += s32b[r];
      }
      ps += __shfl_xor(ps, 32);
      l_run += ps;

      // ---- P -> bf16 B-frags from s32a/s32b (literal-constant indices)
      s8v pf[4];
#define PFMAKE(KS, V, O) do { unsigned c0, c1, c2, c3; \
        asm("v_cvt_pk_bf16_f32 %0, %1, %2" : "=v"(c0) : "v"(V[(O)+0]), "v"(V[(O)+1])); \
        asm("v_cvt_pk_bf16_f32 %0, %1, %2" : "=v"(c1) : "v"(V[(O)+2]), "v"(V[(O)+3])); \
        asm("v_cvt_pk_bf16_f32 %0, %1, %2" : "=v"(c2) : "v"(V[(O)+4]), "v"(V[(O)+5])); \
        asm("v_cvt_pk_bf16_f32 %0, %1, %2" : "=v"(c3) : "v"(V[(O)+6]), "v"(V[(O)+7])); \
        asm volatile("v_permlane32_swap_b32 %0, %1" : "+v"(c0), "+v"(c2)); \
        asm volatile("v_permlane32_swap_b32 %0, %1" : "+v"(c1), "+v"(c3)); \
        u4v pw; pw.x = c0; pw.y = c1; pw.z = c2; pw.w = c3; \
        pf[KS] = __builtin_bit_cast(s8v, pw); } while (0)
      PFMAKE(0, s32a, 0);
      PFMAKE(1, s32a, 8);
      PFMAKE(2, s32b, 0);
      PFMAKE(3, s32b, 8);
#undef PFMAKE

#define PVS(KS, CUR, NXT, LAST) do { \
        if (!(LAST)) { \
          _Pragma("unroll") for (int u = 0; u < 8; ++u) \
            NXT[u] = tr_read(vbt, ((KS)+1)*4096 + (u >> 1) * 256 + (u & 1) * 1024); \
          asm volatile("s_waitcnt lgkmcnt(8)" ::: "memory"); \
        } else { asm volatile("s_waitcnt lgkmcnt(0)" ::: "memory"); } \
        __builtin_amdgcn_sched_barrier(0); \
        __builtin_amdgcn_s_setprio(1); \
        _Pragma("unroll") for (int dt = 0; dt < 4; ++dt) { \
          s8v vf = __builtin_shufflevector(CUR[dt*2], CUR[dt*2+1], 0,1,2,3,4,5,6,7); \
          mfma3216(oacc[dt], vf, pf[KS]); } \
        __builtin_amdgcn_s_setprio(0); \
      } while (0)
      PVS(0, tA, tB, 0);
      PVS(1, tB, tA, 0);
      PVS(2, tA, tB, 0);
      PVS(3, tB, tA, 1);
#undef PVS
    }
    kc = (kc == 2) ? 0 : kc + 1;
  }

  // ---- epilogue: O -> swizzled f32 LDS (2 passes of 2 waves) -> bf16 stores
  asm volatile("s_waitcnt vmcnt(0) lgkmcnt(0)" ::: "memory");
  asm volatile("s_nop 7\n\ts_nop 7\n\ts_nop 7" ::: "memory");
  __syncthreads();
  const float inv = 1.0f / l_run;
  float* Ost = (float*)smem;
  const int er = tid >> 2, ew = (tid & 3) * 32;
#pragma unroll
  for (int p = 0; p < 2; ++p) {
    if ((wv >> 1) == p) {
      const int qip = (wv & 1) * 32 + q31;
#pragma unroll
      for (int dt = 0; dt < 4; ++dt)
#pragma unroll
        for (int r = 0; r < 16; ++r) {
          const int d = dt * 32 + (r & 3) + 8 * ((r >> 2) & 3) + 4 * hi;
          Ost[qip * 128 + (d ^ ((qip & 7) << 2))] = oacc[dt][r] * inv;
        }
    }
    __syncthreads();
    const int sw = (er & 7) << 2;
    f4v av[8];
#pragma unroll
    for (int c = 0; c < 8; ++c)
      av[c] = *(const f4v*)(Ost + er * 128 + ((ew + c * 4) ^ sw));
    u4v r0, r1;
    r0.x = pk2(av[0][0], av[0][1]); r0.y = pk2(av[0][2], av[0][3]);
    r0.z = pk2(av[1][0], av[1][1]); r0.w = pk2(av[1][2], av[1][3]);
    r1.x = pk2(av[2][0], av[2][1]); r1.y = pk2(av[2][2], av[2][3]);
    r1.z = pk2(av[3][0], av[3][1]); r1.w = pk2(av[3][2], av[3][3]);
    u4v r2, r3;
    r2.x = pk2(av[4][0], av[4][1]); r2.y = pk2(av[4][2], av[4][3]);
    r2.z = pk2(av[5][0], av[5][1]); r2.w = pk2(av[5][2], av[5][3]);
    r3.x = pk2(av[6][0], av[6][1]); r3.y = pk2(av[6][2], av[6][3]);
    r3.z = pk2(av[7][0], av[7][1]); r3.w = pk2(av[7][2], av[7][3]);
    unsigned short* dst = ao + (size_t)(b * 2048 + q0 + p * 64 + er) * 4096 + h * 128 + ew;
    *(u4v*)dst = r0;
    *(u4v*)(dst + 8) = r1;
    *(u4v*)(dst + 16) = r2;
    *(u4v*)(dst + 24) = r3;
    __syncthreads();
  }
}

// ---------------------------------------------------------------------------
// Host launcher. Workspace (needs ws_size >= 268,435,456 B):
//   [0,32M)     xb bf16        [32M,80M)   wqkv bf16
//   [80M,112M)  wo bf16        [112M,160M) qkv bf16 single [4096][6144]
//   [160M,193.5M) attn_out bf16 (aob)
//   [240M,248M) k bf16         [248M,256M) v bf16
// ---------------------------------------------------------------------------
extern "C" void kernel_launch(void* const* d_in, const int* in_sizes, int n_in,
                              void* d_out, int out_size, void* d_ws, size_t ws_size,
                              hipStream_t stream) {
  (void)in_sizes; (void)n_in; (void)out_size; (void)ws_size;
  const float* x  = (const float*)d_in[0];
  const float* wq = (const float*)d_in[1];
  const float* wk = (const float*)d_in[2];
  const float* wv = (const float*)d_in[3];
  const float* wo = (const float*)d_in[4];
  const float* fr = (const float*)d_in[5];
  const float* fi = (const float*)d_in[6];

  float* out = (float*)d_out;
  float* xk  = out + 16777216;
  float* xv  = xk + 4194304;

  char* ws = (char*)d_ws;
  unsigned short* xb    = (unsigned short*)(ws);
  unsigned short* wqkvb = (unsigned short*)(ws + 33554432);
  unsigned short* wob   = (unsigned short*)(ws + 83886080);
  unsigned short* qkvb  = (unsigned short*)(ws + 117440512);  // 48MB bf16
  unsigned short* aob   = (unsigned short*)(ws + 167772160);  // 33.5MB bf16
  unsigned short* kbuf  = (unsigned short*)(ws + 251658240);
  unsigned short* vbuf  = (unsigned short*)(ws + 260046848);

  // single merged convert launch
  cvt_all<<<57344, 256, 0, stream>>>(x, wq, wk, wv, wo, xb, wqkvb, wob);

  // qkv: 256x192 tiles, full K -> 512 blocks = 2 exact rounds on 256 CUs
  gemm_qkv<<<512, 512, 0, stream>>>(xb, wqkvb, qkvb);
  // K/V-only rope (Q rotated inside attention at load)
  rope_kv<<<16384, 256, 0, stream>>>(qkvb, fr, fi, kbuf, vbuf, xk, xv);
  attn_fwd<<<dim3(16, 32, 2), 256, 0, stream>>>(qkvb, kbuf, vbuf, fr, fi, aob);
  gemm_bt8<0><<<256, 512, 0, stream>>>(aob, wob, out, 4096, 4096, 4096, 4096, 256);
}